// Round 13
// baseline (292.603 us; speedup 1.0000x reference)
//
#include <hip/hip_runtime.h>

// ---------------------------------------------------------------------------
// MultiScaleFeatureFusion — R13 (= R12 + attn ILP + proj 16-row tiles).
//   scale0: x1 [4,512,16,16]  d=64 C=512 hs=16 Ns=256  R=161
//   scale1: x2 [4,256,32,32]  d=32 C=256 hs=32 Ns=1024 R=97
//   scale2: x3 [4,128,64,64]  d=16 C=128 hs=64 Ns=4096 R=65
// u -> proj (16 rows/block, pipelined x loads) -> mid (upsample s + bilerp +
// bf16 hi/lo pack, k in fragment order) -> attn (split-bf16 MFMA, tiles
// interleaved w/ split accumulator chains) -> final. No-max softmax (exact).
// ---------------------------------------------------------------------------

#define BB 4
#define LOG2E 1.44269504088896340736f

typedef __attribute__((ext_vector_type(8))) short short8;
typedef __attribute__((ext_vector_type(4))) float f32x4;

static constexpr int OFF_UP0 = 0;                        // [4][512]
static constexpr int OFF_UP1 = OFF_UP0 + 4 * 512;
static constexpr int OFF_UP2 = OFF_UP1 + 4 * 256;
static constexpr int OFF_UB0 = OFF_UP2 + 4 * 128;
static constexpr int OFF_UB1 = OFF_UB0 + 4;
static constexpr int OFF_UB2 = OFF_UB1 + 4;
static constexpr int OFF_PROJ0 = OFF_UB2 + 4;
static constexpr int OFF_PROJ1 = OFF_PROJ0 + BB * 161 * 256;
static constexpr int OFF_PROJ2 = OFF_PROJ1 + BB * 97 * 1024;
static constexpr int OFF_SBIG0 = OFF_PROJ2 + BB * 65 * 4096;   // [b][4096]
static constexpr int OFF_SBIG1 = OFF_SBIG0 + BB * 4096;        // [b][4096]
static constexpr int OFF_QP0 = OFF_SBIG1 + BB * 4096;          // BB*4096*64 fl
static constexpr int OFF_KF0 = OFF_QP0 + BB * 4096 * 64;       // BB*262144 fl
static constexpr int OFF_QP1 = OFF_KF0 + BB * 262144;          // BB*4096*32 fl
static constexpr int OFF_KF1 = OFF_QP1 + BB * 4096 * 32;       // BB*131072 fl
static constexpr int OFF_QP2 = OFF_KF1 + BB * 131072;          // BB*4096*16 fl
static constexpr int OFF_KF2 = OFF_QP2 + BB * 4096 * 16;       // BB*131072 fl
static constexpr int PS = BB * 4 * 4096;
static constexpr int OFF_PSN0 = OFF_KF2 + BB * 131072;
static constexpr int OFF_PSW0 = OFF_PSN0 + PS;
static constexpr int OFF_PSN1 = OFF_PSW0 + PS;
static constexpr int OFF_PSW1 = OFF_PSN1 + PS;
static constexpr int OFF_PSN2 = OFF_PSW1 + PS;
static constexpr int OFF_PSW2 = OFF_PSN2 + PS;

// --------------------------- u partials ------------------------------------
struct UArgs {
    const float *wv0, *wa0, *bv0;
    const float *wv1, *wa1, *bv1;
    const float *wv2, *wa2, *bv2;
    float* ws;
};

__global__ void u_kernel(UArgs A) {
    __shared__ float red[256];
    int idx = blockIdx.x, tid = threadIdx.x;
    int C, cit, chunk;
    const float *wv, *wa, *bv;
    float *up, *ub;
    if (idx < 32) {
        C = 512; cit = idx >> 2; chunk = idx & 3;
        wv = A.wv0; wa = A.wa0; bv = A.bv0;
        up = A.ws + OFF_UP0; ub = A.ws + OFF_UB0;
    } else if (idx < 48) {
        int i2 = idx - 32;
        C = 256; cit = i2 >> 2; chunk = i2 & 3;
        wv = A.wv1; wa = A.wa1; bv = A.bv1;
        up = A.ws + OFF_UP1; ub = A.ws + OFF_UB1;
    } else {
        int i2 = idx - 48;
        C = 128; cit = i2 >> 2; chunk = i2 & 3;
        wv = A.wv2; wa = A.wa2; bv = A.bv2;
        up = A.ws + OFF_UP2; ub = A.ws + OFF_UB2;
    }
    int lci = tid & 63, sub = tid >> 6;
    int ci = cit * 64 + lci;
    int coBeg = chunk * (C >> 2), coEnd = coBeg + (C >> 2);
    float acc = 0.f;
#pragma unroll 4
    for (int co = coBeg + sub; co < coEnd; co += 4)
        acc += wa[co] * wv[(size_t)co * C + ci];
    red[tid] = acc;
    __syncthreads();
    if (sub == 0)
        up[chunk * C + ci] = red[lci] + red[lci + 64] + red[lci + 128] + red[lci + 192];
    if (cit == 0) {
        __syncthreads();
        float bacc = 0.f;
        for (int co = coBeg + tid; co < coEnd; co += 256) bacc += wa[co] * bv[co];
        red[tid] = bacc;
        __syncthreads();
        for (int off = 128; off > 0; off >>= 1) {
            if (tid < off) red[tid] += red[tid + off];
            __syncthreads();
        }
        if (tid == 0) ub[chunk] = red[0];
    }
}

// --------------------------- proj: all scales, 16 rows/block ---------------
struct ProjArgs {
    const float *x0, *x1, *x2;
    const float *wq0, *wk0, *bq0, *bk0;
    const float *wq1, *wk1, *bq1, *bk1;
    const float *wq2, *wk2, *bq2, *bk2;
    const float *w1;
    float* ws;
};

__global__ __launch_bounds__(256) void proj_kernel(ProjArgs A) {
    __shared__ __align__(16) float Wl[512 * 16];  // [c][rr], 64B per c
    __shared__ float bl[16];
    __shared__ float red[4096];
    int idx = blockIdx.x, tid = threadIdx.x;
    const float *x, *wq, *wk, *bq, *bk, *up, *ub;
    float* out;
    int C, Ns, R, nx, d, w1off, local;
    if (idx < 44) {
        local = idx; x = A.x0; out = A.ws + OFF_PROJ0;
        wq = A.wq0; wk = A.wk0; bq = A.bq0; bk = A.bk0;
        up = A.ws + OFF_UP0; ub = A.ws + OFF_UB0;
        C = 512; Ns = 256; R = 161; nx = 1; d = 64; w1off = 384;
    } else if (idx < 156) {
        local = idx - 44; x = A.x1; out = A.ws + OFF_PROJ1;
        wq = A.wq1; wk = A.wk1; bq = A.bq1; bk = A.bk1;
        up = A.ws + OFF_UP1; ub = A.ws + OFF_UB1;
        C = 256; Ns = 1024; R = 97; nx = 4; d = 32; w1off = 128;
    } else {
        local = idx - 156; x = A.x2; out = A.ws + OFF_PROJ2;
        wq = A.wq2; wk = A.wk2; bq = A.bq2; bk = A.bk2;
        up = A.ws + OFF_UP2; ub = A.ws + OFF_UB2;
        C = 128; Ns = 4096; R = 65; nx = 16; d = 16; w1off = 0;
    }
    int ny = (R + 15) >> 4;
    int pb = nx * ny;
    int b = local / pb;
    int rem = local - b * pb;
    int by = rem / nx;
    int bx = rem - by * nx;
    int r0 = by * 16;
    int nr = min(16, R - r0);
    // stage 16 rows (2 passes of 8), 32 c-lanes each
    for (int rp = 0; rp < 16; rp += 8) {
        int rr = rp + (tid >> 5), cg = tid & 31;
        int gr = r0 + rr;
        if (gr == 2 * d) {
            for (int c = cg; c < C; c += 32)
                Wl[c * 16 + rr] = up[c] + up[C + c] + up[2 * C + c] + up[3 * C + c];
        } else {
            const float* rowsrc;
            if (gr < d) rowsrc = wq + (size_t)gr * C;
            else if (gr < 2 * d) rowsrc = wk + (size_t)(gr - d) * C;
            else if (gr < R) rowsrc = A.w1 + (size_t)(gr - 2 * d - 1) * 896 + w1off;
            else rowsrc = nullptr;
            if (rowsrc) {
                for (int c = cg; c < C; c += 32) Wl[c * 16 + rr] = rowsrc[c];
            } else {
                for (int c = cg; c < C; c += 32) Wl[c * 16 + rr] = 0.f;
            }
        }
    }
    if (tid < 16) {
        int g2 = r0 + tid;
        float bv2;
        if (g2 < d) bv2 = bq[g2];
        else if (g2 < 2 * d) bv2 = bk[g2 - d];
        else if (g2 == 2 * d) bv2 = ub[0] + ub[1] + ub[2] + ub[3];
        else bv2 = 0.f;
        bl[tid] = bv2;
    }
    __syncthreads();
    int lane = tid & 63, strip = tid >> 6;
    int m0 = bx * 256 + lane * 4;
    const float* xb = x + (size_t)(b * C) * Ns + m0;
    float acc[16][4];
#pragma unroll
    for (int r = 0; r < 16; ++r)
#pragma unroll
        for (int j = 0; j < 4; ++j) acc[r][j] = 0.f;
    float4 buf[4];
#pragma unroll
    for (int j = 0; j < 4; ++j)
        buf[j] = *(const float4*)&xb[(size_t)(strip + 4 * j) * Ns];
    for (int c0 = strip; c0 < C; c0 += 16) {
#pragma unroll
        for (int j = 0; j < 4; ++j) {
            int c = c0 + 4 * j;
            float4 xv = buf[j];
            int cn = c + 16;
            if (cn < C) buf[j] = *(const float4*)&xb[(size_t)cn * Ns];
            const float* wl = &Wl[c * 16];
#pragma unroll
            for (int r4 = 0; r4 < 4; ++r4) {
                float4 w = *(const float4*)&wl[r4 * 4];
                acc[r4 * 4 + 0][0] += w.x * xv.x; acc[r4 * 4 + 0][1] += w.x * xv.y;
                acc[r4 * 4 + 0][2] += w.x * xv.z; acc[r4 * 4 + 0][3] += w.x * xv.w;
                acc[r4 * 4 + 1][0] += w.y * xv.x; acc[r4 * 4 + 1][1] += w.y * xv.y;
                acc[r4 * 4 + 1][2] += w.y * xv.z; acc[r4 * 4 + 1][3] += w.y * xv.w;
                acc[r4 * 4 + 2][0] += w.z * xv.x; acc[r4 * 4 + 2][1] += w.z * xv.y;
                acc[r4 * 4 + 2][2] += w.z * xv.z; acc[r4 * 4 + 2][3] += w.z * xv.w;
                acc[r4 * 4 + 3][0] += w.w * xv.x; acc[r4 * 4 + 3][1] += w.w * xv.y;
                acc[r4 * 4 + 3][2] += w.w * xv.z; acc[r4 * 4 + 3][3] += w.w * xv.w;
            }
        }
    }
    // strip-reduce 4 rows per round
    for (int rp = 0; rp < 16; rp += 4) {
        __syncthreads();
#pragma unroll
        for (int r = 0; r < 4; ++r)
#pragma unroll
            for (int j = 0; j < 4; ++j)
                red[((r * 4 + j) * 4 + strip) * 64 + lane] = acc[rp + r][j];
        __syncthreads();
        int g = tid >> 6;
        int rr2 = rp + g;
        if (rr2 < nr) {
            float v[4];
#pragma unroll
            for (int j = 0; j < 4; ++j) {
                int base = (g * 4 + j) * 4 * 64 + lane;
                v[j] = red[base] + red[base + 64] + red[base + 128] + red[base + 192] + bl[rr2];
            }
            *(float4*)&out[(size_t)(b * R + r0 + rr2) * Ns + m0] =
                make_float4(v[0], v[1], v[2], v[3]);
        }
    }
}

// --------------------------- hi/lo split helper ----------------------------
__device__ inline void split_bf16(float f, ushort& hi, ushort& lo) {
    unsigned u = __float_as_uint(f);
    unsigned h = u >> 16;
    float r = f - __uint_as_float(h << 16);
    hi = (ushort)h;
    lo = (ushort)(__float_as_uint(r) >> 16);
}

// --------------------------- bilerp field values ---------------------------
template <int D, int HS>
__device__ void bilerp_vals(const float* __restrict__ proj, int R, int rowbase,
                            float scale, int b, int n, float* vals) {
    constexpr int NS = HS * HS;
    constexpr float f = (float)(HS - 1) / 63.0f;
    int oy = n >> 6, ox = n & 63;
    float cy = oy * f, cx = ox * f;
    int iy0 = min((int)cy, HS - 2);
    int ix0 = min((int)cx, HS - 2);
    float wy = cy - iy0, wx = cx - ix0;
    float w00 = (1.f - wy) * (1.f - wx) * scale, w01 = (1.f - wy) * wx * scale;
    float w10 = wy * (1.f - wx) * scale, w11 = wy * wx * scale;
    const float* pb = proj + ((size_t)b * R + rowbase) * NS + iy0 * HS + ix0;
#pragma unroll
    for (int d = 0; d < D; ++d) {
        const float* p = pb + (size_t)d * NS;
        vals[d] = w00 * p[0] + w01 * p[1] + w10 * p[HS] + w11 * p[HS + 1];
    }
}

// --------------------------- q pack ([n][2D] layout) -----------------------
template <int D>
__device__ void q_store(ushort* __restrict__ dst, const float* vals, int b, int n) {
    ushort outv[2 * D];
#pragma unroll
    for (int d = 0; d < D; ++d) split_bf16(vals[d], outv[d], outv[D + d]);
    ushort* dp = dst + (size_t)(b * 4096 + n) * (2 * D);
#pragma unroll
    for (int i = 0; i < D / 4; ++i)
        ((uint4*)dp)[i] = ((const uint4*)outv)[i];
}

// --------------------------- k pack (fragment order) -----------------------
template <int D>
__device__ void k_store(ushort* __restrict__ dst, const float* vals, int b, int n) {
    constexpr int NC = (D == 16) ? 2 : (D / 32) * 2;
    ushort hi[D], lo[D];
#pragma unroll
    for (int d = 0; d < D; ++d) split_bf16(vals[d], hi[d], lo[d]);
    int tile = n >> 4, cc = n & 15;
    ushort* kb = dst + (size_t)b * (256 * NC * 512) + (size_t)tile * (NC * 512);
    if constexpr (D == 16) {
#pragma unroll
        for (int combo = 0; combo < 2; ++combo)
#pragma unroll
            for (int quad = 0; quad < 4; ++quad) {
                const ushort* src = (combo == 0 ? hi : lo) + (quad & 1) * 8;
                ushort* dp = kb + ((size_t)combo * 512 + (quad * 16 + cc) * 8);
                *(uint4*)dp = *(const uint4*)src;
            }
    } else {
#pragma unroll
        for (int h = 0; h < D / 32; ++h)
#pragma unroll
            for (int part = 0; part < 2; ++part) {
                int combo = h * 2 + part;
#pragma unroll
                for (int quad = 0; quad < 4; ++quad) {
                    const ushort* src = (part == 0 ? hi : lo) + h * 32 + quad * 8;
                    ushort* dp = kb + ((size_t)combo * 512 + (quad * 16 + cc) * 8);
                    *(uint4*)dp = *(const uint4*)src;
                }
            }
    }
}

// --------------------------- native field values (scale2) ------------------
__device__ void nat_vals(const float* __restrict__ proj, int rowbase, float scale,
                         int b, int n, float* vals) {
    const float* pb = proj + ((size_t)b * 65 + rowbase) * 4096 + n;
#pragma unroll
    for (int d = 0; d < 16; ++d) vals[d] = pb[(size_t)d * 4096] * scale;
}

// --------------------------- mid: upsample-s + packs -----------------------
__global__ __launch_bounds__(256) void mid_kernel(float* ws) {
    int idx = blockIdx.x, tid = threadIdx.x;
    if (idx < 128) {
        int gi = idx * 256 + tid;
        int seg = gi >> 14;
        int li = gi & 16383;
        int b = li >> 12, n = li & 4095;
        const float* src;
        float* dst;
        int hs;
        if (seg == 0) { src = ws + OFF_PROJ0 + (b * 161 + 128) * 256;  dst = ws + OFF_SBIG0; hs = 16; }
        else          { src = ws + OFF_PROJ1 + (b * 97 + 64) * 1024;   dst = ws + OFF_SBIG1; hs = 32; }
        int oy = n >> 6, ox = n & 63;
        float f = (float)(hs - 1) / 63.0f;
        float cy = oy * f, cx = ox * f;
        int iy0 = min((int)cy, hs - 2);
        int ix0 = min((int)cx, hs - 2);
        float wy = cy - iy0, wx = cx - ix0;
        float v00 = src[iy0 * hs + ix0], v01 = src[iy0 * hs + ix0 + 1];
        float v10 = src[(iy0 + 1) * hs + ix0], v11 = src[(iy0 + 1) * hs + ix0 + 1];
        float t0 = v00 + wx * (v01 - v00), t1 = v10 + wx * (v11 - v10);
        dst[b * 4096 + n] = t0 + wy * (t1 - t0);
    } else if (idx < 256) {
        int li = idx - 128;
        int field = li >> 6, b = (li >> 4) & 3, nt = li & 15;
        int n = nt * 256 + tid;
        float vals[64];
        if (field == 0) {
            bilerp_vals<64, 16>(ws + OFF_PROJ0, 161, 0, LOG2E, b, n, vals);
            q_store<64>((ushort*)(ws + OFF_QP0), vals, b, n);
        } else {
            bilerp_vals<64, 16>(ws + OFF_PROJ0, 161, 64, 1.0f, b, n, vals);
            k_store<64>((ushort*)(ws + OFF_KF0), vals, b, n);
        }
    } else if (idx < 384) {
        int li = idx - 256;
        int field = li >> 6, b = (li >> 4) & 3, nt = li & 15;
        int n = nt * 256 + tid;
        float vals[32];
        if (field == 0) {
            bilerp_vals<32, 32>(ws + OFF_PROJ1, 97, 0, LOG2E, b, n, vals);
            q_store<32>((ushort*)(ws + OFF_QP1), vals, b, n);
        } else {
            bilerp_vals<32, 32>(ws + OFF_PROJ1, 97, 32, 1.0f, b, n, vals);
            k_store<32>((ushort*)(ws + OFF_KF1), vals, b, n);
        }
    } else {
        int li = idx - 384;
        int field = li >> 6, b = (li >> 4) & 3, nt = li & 15;
        int n = nt * 256 + tid;
        float vals[16];
        if (field == 0) {
            nat_vals(ws + OFF_PROJ2, 0, LOG2E, b, n, vals);
            q_store<16>((ushort*)(ws + OFF_QP2), vals, b, n);
        } else {
            nat_vals(ws + OFF_PROJ2, 16, 1.0f, b, n, vals);
            k_store<16>((ushort*)(ws + OFF_KF2), vals, b, n);
        }
    }
}

// --------------------------- MFMA attention body ---------------------------
// Wave = 16-n tile over 1024-m chunk, fragment-ordered k. Tiles interleaved
// (NT) with split accumulator chains for MFMA-latency hiding. Exact
// split-bf16 product. C: col=lane&15 (m), row=quad*4+reg (n).
template <int D>
__device__ void attn_mfma_body(const ushort* __restrict__ qp, const ushort* __restrict__ kf,
                               const float* __restrict__ srow,
                               float* __restrict__ pSn, float* __restrict__ pSw,
                               int nblk, int mc, int b, int tid) {
    constexpr int NC = (D == 16) ? 2 : (D / 32) * 2;
    constexpr int NT = (D == 16) ? 4 : 2;
    int wave = tid >> 6, lane = tid & 63;
    int cc = lane & 15, quad = lane >> 4;
    int n0 = (nblk * 4 + wave) * 16;
    const ushort* qn = qp + (size_t)(b * 4096 + n0 + cc) * (2 * D);
    constexpr int NF = (D >= 32) ? (D / 32) : 1;
    short8 Ah[NF], Al[NF];
    if constexpr (D == 16) {
        Ah[0] = *(const short8*)(qn + quad * 8);   // [qh16|ql16] spans k=0..31
    } else {
#pragma unroll
        for (int h = 0; h < NF; ++h) {
            Ah[h] = *(const short8*)(qn + h * 32 + quad * 8);
            Al[h] = *(const short8*)(qn + D + h * 32 + quad * 8);
        }
    }
    const ushort* kfb = kf + (size_t)b * (256 * NC * 512) + lane * 8;
    float Sn[4] = {0.f, 0.f, 0.f, 0.f};
    float Sw[4] = {0.f, 0.f, 0.f, 0.f};
    int tbase = mc * 64;
#pragma unroll 2
    for (int mt = 0; mt < 64; mt += NT) {
        float sv[NT];
#pragma unroll
        for (int t = 0; t < NT; ++t)
            sv[t] = srow[(tbase + mt + t) * 16 + cc];
        f32x4 cr[NT];
        if constexpr (D == 16) {
#pragma unroll
            for (int t = 0; t < NT; ++t) {
                const ushort* kt = kfb + (size_t)(tbase + mt + t) * (NC * 512);
                short8 b1 = *(const short8*)(kt);
                short8 b2 = *(const short8*)(kt + 512);
                f32x4 c = {0.f, 0.f, 0.f, 0.f};
                c = __builtin_amdgcn_mfma_f32_16x16x32_bf16(Ah[0], b1, c, 0, 0, 0);
                c = __builtin_amdgcn_mfma_f32_16x16x32_bf16(Ah[0], b2, c, 0, 0, 0);
                cr[t] = c;
            }
        } else if constexpr (D == 32) {
#pragma unroll
            for (int t = 0; t < NT; ++t) {
                const ushort* kt = kfb + (size_t)(tbase + mt + t) * (NC * 512);
                short8 Bh = *(const short8*)(kt);
                short8 Bl = *(const short8*)(kt + 512);
                f32x4 ca = {0.f, 0.f, 0.f, 0.f};
                f32x4 cb = {0.f, 0.f, 0.f, 0.f};
                ca = __builtin_amdgcn_mfma_f32_16x16x32_bf16(Ah[0], Bh, ca, 0, 0, 0);
                cb = __builtin_amdgcn_mfma_f32_16x16x32_bf16(Ah[0], Bl, cb, 0, 0, 0);
                ca = __builtin_amdgcn_mfma_f32_16x16x32_bf16(Al[0], Bl, ca, 0, 0, 0);
                cb = __builtin_amdgcn_mfma_f32_16x16x32_bf16(Al[0], Bh, cb, 0, 0, 0);
                cr[t] = ca + cb;
            }
        } else {  // D == 64
#pragma unroll
            for (int t = 0; t < NT; ++t) {
                const ushort* kt = kfb + (size_t)(tbase + mt + t) * (NC * 512);
                short8 Bh0 = *(const short8*)(kt);
                short8 Bl0 = *(const short8*)(kt + 512);
                short8 Bh1 = *(const short8*)(kt + 1024);
                short8 Bl1 = *(const short8*)(kt + 1536);
                f32x4 ca = {0.f, 0.f, 0.f, 0.f};
                f32x4 cb = {0.f, 0.f, 0.f, 0.f};
                ca = __builtin_amdgcn_mfma_f32_16x16x32_bf16(Ah[0], Bh0, ca, 0, 0, 0);
                cb = __builtin_amdgcn_mfma_f32_16x16x32_bf16(Ah[1], Bh1, cb, 0, 0, 0);
                ca = __builtin_amdgcn_mfma_f32_16x16x32_bf16(Ah[0], Bl0, ca, 0, 0, 0);
                cb = __builtin_amdgcn_mfma_f32_16x16x32_bf16(Ah[1], Bl1, cb, 0, 0, 0);
                ca = __builtin_amdgcn_mfma_f32_16x16x32_bf16(Al[0], Bh0, ca, 0, 0, 0);
                cb = __builtin_amdgcn_mfma_f32_16x16x32_bf16(Al[1], Bh1, cb, 0, 0, 0);
                ca = __builtin_amdgcn_mfma_f32_16x16x32_bf16(Al[0], Bl0, ca, 0, 0, 0);
                cb = __builtin_amdgcn_mfma_f32_16x16x32_bf16(Al[1], Bl1, cb, 0, 0, 0);
                cr[t] = ca + cb;
            }
        }
#pragma unroll
        for (int t = 0; t < NT; ++t) {
#pragma unroll
            for (int r = 0; r < 4; ++r) {
                float e = exp2f(cr[t][r]);
                Sn[r] += e;
                Sw[r] += e * sv[t];
            }
        }
    }
#pragma unroll
    for (int mask = 1; mask < 16; mask <<= 1) {
#pragma unroll
        for (int r = 0; r < 4; ++r) {
            Sn[r] += __shfl_xor(Sn[r], mask, 64);
            Sw[r] += __shfl_xor(Sw[r], mask, 64);
        }
    }
    if (cc == 0) {
        int n = n0 + quad * 4;
        int pidx = (b * 4 + mc) * 4096 + n;
        *(float4*)&pSn[pidx] = make_float4(Sn[0], Sn[1], Sn[2], Sn[3]);
        *(float4*)&pSw[pidx] = make_float4(Sw[0], Sw[1], Sw[2], Sw[3]);
    }
}

// --------------------------- attn: all three scales ------------------------
__global__ __launch_bounds__(256) void attn_kernel(float* ws) {
    int idx = blockIdx.x, tid = threadIdx.x;
    int li = idx & 1023;
    int nblk = li & 63, mc = (li >> 6) & 3, b = li >> 8;
    if (idx < 1024) {
        attn_mfma_body<64>((const ushort*)(ws + OFF_QP0), (const ushort*)(ws + OFF_KF0),
                           ws + OFF_SBIG0 + b * 4096,
                           ws + OFF_PSN0, ws + OFF_PSW0, nblk, mc, b, tid);
    } else if (idx < 2048) {
        attn_mfma_body<32>((const ushort*)(ws + OFF_QP1), (const ushort*)(ws + OFF_KF1),
                           ws + OFF_SBIG1 + b * 4096,
                           ws + OFF_PSN1, ws + OFF_PSW1, nblk, mc, b, tid);
    } else {
        attn_mfma_body<16>((const ushort*)(ws + OFF_QP2), (const ushort*)(ws + OFF_KF2),
                           ws + OFF_PROJ2 + ((size_t)b * 65 + 32) * 4096,
                           ws + OFF_PSN2, ws + OFF_PSW2, nblk, mc, b, tid);
    }
}

// --------------------------- final: combine + fusion -----------------------
__global__ __launch_bounds__(256) void final_kernel(const float* __restrict__ ws,
                                                    const float* __restrict__ ba0,
                                                    const float* __restrict__ ba1,
                                                    const float* __restrict__ ba2,
                                                    const float* __restrict__ b1,
                                                    const float* __restrict__ w2,
                                                    const float* __restrict__ b2,
                                                    float* __restrict__ out) {
    __shared__ float lb1[32], lw2[32];
    int tid = threadIdx.x;
    if (tid < 32) { lb1[tid] = b1[tid]; lw2[tid] = w2[tid]; }
    __syncthreads();
    int b = blockIdx.y;
    int n = blockIdx.x * 256 + tid;
    const float* pSns[3] = {ws + OFF_PSN0, ws + OFF_PSN1, ws + OFF_PSN2};
    const float* pSws[3] = {ws + OFF_PSW0, ws + OFF_PSW1, ws + OFF_PSW2};
    float aval[3];
#pragma unroll
    for (int s = 0; s < 3; ++s) {
        float Sn = 0.f, Sw = 0.f;
#pragma unroll
        for (int ch = 0; ch < 4; ++ch) {
            int pi = (b * 4 + ch) * 4096 + n;
            Sn += pSns[s][pi];
            Sw += pSws[s][pi];
        }
        float bav = (s == 0) ? ba0[0] : (s == 1) ? ba1[0] : ba2[0];
        aval[s] = Sw / Sn + bav;
    }
    float prod = aval[0] * aval[1] * aval[2];
    int oy = n >> 6, ox = n & 63;
    float f0 = 15.0f / 63.0f;
    float cy0 = oy * f0, cx0 = ox * f0;
    int iy0 = min((int)cy0, 14), ix0 = min((int)cx0, 14);
    float wy0 = cy0 - iy0, wx0 = cx0 - ix0;
    float f1 = 31.0f / 63.0f;
    float cy1 = oy * f1, cx1 = ox * f1;
    int iy1 = min((int)cy1, 30), ix1 = min((int)cx1, 30);
    float wy1 = cy1 - iy1, wx1 = cx1 - ix1;
    const float* g0b = ws + OFF_PROJ0 + (b * 161 + 129) * 256;
    const float* g1b = ws + OFF_PROJ1 + (b * 97 + 65) * 1024;
    const float* g2b = ws + OFF_PROJ2 + (b * 65 + 33) * 4096;
    float outv = 0.f;
#pragma unroll 4
    for (int j = 0; j < 32; ++j) {
        const float* p0 = g0b + j * 256;
        float v0 = (1.f - wy0) * ((1.f - wx0) * p0[iy0 * 16 + ix0] + wx0 * p0[iy0 * 16 + ix0 + 1]) +
                   wy0 * ((1.f - wx0) * p0[(iy0 + 1) * 16 + ix0] + wx0 * p0[(iy0 + 1) * 16 + ix0 + 1]);
        const float* p1 = g1b + j * 1024;
        float v1 = (1.f - wy1) * ((1.f - wx1) * p1[iy1 * 32 + ix1] + wx1 * p1[iy1 * 32 + ix1 + 1]) +
                   wy1 * ((1.f - wx1) * p1[(iy1 + 1) * 32 + ix1] + wx1 * p1[(iy1 + 1) * 32 + ix1 + 1]);
        float g = g2b[j * 4096 + n] + v0 + v1;
        float h = fmaxf(prod * g + lb1[j], 0.f);
        outv += lw2[j] * h;
    }
    out[b * 4096 + n] = outv + b2[0];
}

// ---------------------------------------------------------------------------
extern "C" void kernel_launch(void* const* d_in, const int* in_sizes, int n_in,
                              void* d_out, int out_size, void* d_ws, size_t ws_size,
                              hipStream_t stream) {
    const float* x3 = (const float*)d_in[0];
    const float* x2 = (const float*)d_in[1];
    const float* x1 = (const float*)d_in[2];
    const float* W[24];
    for (int i = 0; i < 24; ++i) W[i] = (const float*)d_in[3 + i];
    const float* w1 = (const float*)d_in[27];
    const float* b1 = (const float*)d_in[28];
    const float* w2 = (const float*)d_in[29];
    const float* b2 = (const float*)d_in[30];
    float* ws = (float*)d_ws;
    float* out = (float*)d_out;

    UArgs ua;
    ua.wv0 = W[4];  ua.wa0 = W[6];  ua.bv0 = W[5];
    ua.wv1 = W[12]; ua.wa1 = W[14]; ua.bv1 = W[13];
    ua.wv2 = W[20]; ua.wa2 = W[22]; ua.bv2 = W[21];
    ua.ws = ws;
    u_kernel<<<56, 256, 0, stream>>>(ua);

    ProjArgs ja;
    ja.x0 = x1; ja.x1 = x2; ja.x2 = x3;
    ja.wq0 = W[0];  ja.wk0 = W[2];  ja.bq0 = W[1];  ja.bk0 = W[3];
    ja.wq1 = W[8];  ja.wk1 = W[10]; ja.bq1 = W[9];  ja.bk1 = W[11];
    ja.wq2 = W[16]; ja.wk2 = W[18]; ja.bq2 = W[17]; ja.bk2 = W[19];
    ja.w1 = w1; ja.ws = ws;
    proj_kernel<<<476, 256, 0, stream>>>(ja);

    mid_kernel<<<512, 256, 0, stream>>>(ws);

    attn_kernel<<<3072, 256, 0, stream>>>(ws);

    final_kernel<<<dim3(16, BB), 256, 0, stream>>>(ws, W[7], W[15], W[23],
                                                   b1, w2, b2, out);
}

// Round 14
// 276.357 us; speedup vs baseline: 1.0588x; 1.0588x over previous
//
#include <hip/hip_runtime.h>

// ---------------------------------------------------------------------------
// MultiScaleFeatureFusion — R14 (= R13 proj + R12 attn + reg prefetch).
//   scale0: x1 [4,512,16,16]  d=64 C=512 hs=16 Ns=256  R=161
//   scale1: x2 [4,256,32,32]  d=32 C=256 hs=32 Ns=1024 R=97
//   scale2: x3 [4,128,64,64]  d=16 C=128 hs=64 Ns=4096 R=65
// u -> proj (16 rows/block) -> mid (upsample s + bilerp + bf16 hi/lo pack,
// k in fragment order) -> attn (split-bf16 MFMA, single accumulator per tile
// [keeps VGPR<64 / 8 waves], one-tile-ahead register prefetch of k frags+s)
// -> final. No-max softmax (exact: logits bounded, scale cancels in Sw/Sn).
// ---------------------------------------------------------------------------

#define BB 4
#define LOG2E 1.44269504088896340736f

typedef __attribute__((ext_vector_type(8))) short short8;
typedef __attribute__((ext_vector_type(4))) float f32x4;

static constexpr int OFF_UP0 = 0;                        // [4][512]
static constexpr int OFF_UP1 = OFF_UP0 + 4 * 512;
static constexpr int OFF_UP2 = OFF_UP1 + 4 * 256;
static constexpr int OFF_UB0 = OFF_UP2 + 4 * 128;
static constexpr int OFF_UB1 = OFF_UB0 + 4;
static constexpr int OFF_UB2 = OFF_UB1 + 4;
static constexpr int OFF_PROJ0 = OFF_UB2 + 4;
static constexpr int OFF_PROJ1 = OFF_PROJ0 + BB * 161 * 256;
static constexpr int OFF_PROJ2 = OFF_PROJ1 + BB * 97 * 1024;
static constexpr int OFF_SBIG0 = OFF_PROJ2 + BB * 65 * 4096;   // [b][4096]
static constexpr int OFF_SBIG1 = OFF_SBIG0 + BB * 4096;        // [b][4096]
static constexpr int OFF_QP0 = OFF_SBIG1 + BB * 4096;          // BB*4096*64 fl
static constexpr int OFF_KF0 = OFF_QP0 + BB * 4096 * 64;       // BB*262144 fl
static constexpr int OFF_QP1 = OFF_KF0 + BB * 262144;          // BB*4096*32 fl
static constexpr int OFF_KF1 = OFF_QP1 + BB * 4096 * 32;       // BB*131072 fl
static constexpr int OFF_QP2 = OFF_KF1 + BB * 131072;          // BB*4096*16 fl
static constexpr int OFF_KF2 = OFF_QP2 + BB * 4096 * 16;       // BB*131072 fl
static constexpr int PS = BB * 4 * 4096;
static constexpr int OFF_PSN0 = OFF_KF2 + BB * 131072;
static constexpr int OFF_PSW0 = OFF_PSN0 + PS;
static constexpr int OFF_PSN1 = OFF_PSW0 + PS;
static constexpr int OFF_PSW1 = OFF_PSN1 + PS;
static constexpr int OFF_PSN2 = OFF_PSW1 + PS;
static constexpr int OFF_PSW2 = OFF_PSN2 + PS;

// --------------------------- u partials ------------------------------------
struct UArgs {
    const float *wv0, *wa0, *bv0;
    const float *wv1, *wa1, *bv1;
    const float *wv2, *wa2, *bv2;
    float* ws;
};

__global__ void u_kernel(UArgs A) {
    __shared__ float red[256];
    int idx = blockIdx.x, tid = threadIdx.x;
    int C, cit, chunk;
    const float *wv, *wa, *bv;
    float *up, *ub;
    if (idx < 32) {
        C = 512; cit = idx >> 2; chunk = idx & 3;
        wv = A.wv0; wa = A.wa0; bv = A.bv0;
        up = A.ws + OFF_UP0; ub = A.ws + OFF_UB0;
    } else if (idx < 48) {
        int i2 = idx - 32;
        C = 256; cit = i2 >> 2; chunk = i2 & 3;
        wv = A.wv1; wa = A.wa1; bv = A.bv1;
        up = A.ws + OFF_UP1; ub = A.ws + OFF_UB1;
    } else {
        int i2 = idx - 48;
        C = 128; cit = i2 >> 2; chunk = i2 & 3;
        wv = A.wv2; wa = A.wa2; bv = A.bv2;
        up = A.ws + OFF_UP2; ub = A.ws + OFF_UB2;
    }
    int lci = tid & 63, sub = tid >> 6;
    int ci = cit * 64 + lci;
    int coBeg = chunk * (C >> 2), coEnd = coBeg + (C >> 2);
    float acc = 0.f;
#pragma unroll 4
    for (int co = coBeg + sub; co < coEnd; co += 4)
        acc += wa[co] * wv[(size_t)co * C + ci];
    red[tid] = acc;
    __syncthreads();
    if (sub == 0)
        up[chunk * C + ci] = red[lci] + red[lci + 64] + red[lci + 128] + red[lci + 192];
    if (cit == 0) {
        __syncthreads();
        float bacc = 0.f;
        for (int co = coBeg + tid; co < coEnd; co += 256) bacc += wa[co] * bv[co];
        red[tid] = bacc;
        __syncthreads();
        for (int off = 128; off > 0; off >>= 1) {
            if (tid < off) red[tid] += red[tid + off];
            __syncthreads();
        }
        if (tid == 0) ub[chunk] = red[0];
    }
}

// --------------------------- proj: all scales, 16 rows/block ---------------
struct ProjArgs {
    const float *x0, *x1, *x2;
    const float *wq0, *wk0, *bq0, *bk0;
    const float *wq1, *wk1, *bq1, *bk1;
    const float *wq2, *wk2, *bq2, *bk2;
    const float *w1;
    float* ws;
};

__global__ __launch_bounds__(256) void proj_kernel(ProjArgs A) {
    __shared__ __align__(16) float Wl[512 * 16];  // [c][rr]
    __shared__ float bl[16];
    __shared__ float red[4096];
    int idx = blockIdx.x, tid = threadIdx.x;
    const float *x, *wq, *wk, *bq, *bk, *up, *ub;
    float* out;
    int C, Ns, R, nx, d, w1off, local;
    if (idx < 44) {
        local = idx; x = A.x0; out = A.ws + OFF_PROJ0;
        wq = A.wq0; wk = A.wk0; bq = A.bq0; bk = A.bk0;
        up = A.ws + OFF_UP0; ub = A.ws + OFF_UB0;
        C = 512; Ns = 256; R = 161; nx = 1; d = 64; w1off = 384;
    } else if (idx < 156) {
        local = idx - 44; x = A.x1; out = A.ws + OFF_PROJ1;
        wq = A.wq1; wk = A.wk1; bq = A.bq1; bk = A.bk1;
        up = A.ws + OFF_UP1; ub = A.ws + OFF_UB1;
        C = 256; Ns = 1024; R = 97; nx = 4; d = 32; w1off = 128;
    } else {
        local = idx - 156; x = A.x2; out = A.ws + OFF_PROJ2;
        wq = A.wq2; wk = A.wk2; bq = A.bq2; bk = A.bk2;
        up = A.ws + OFF_UP2; ub = A.ws + OFF_UB2;
        C = 128; Ns = 4096; R = 65; nx = 16; d = 16; w1off = 0;
    }
    int ny = (R + 15) >> 4;
    int pb = nx * ny;
    int b = local / pb;
    int rem = local - b * pb;
    int by = rem / nx;
    int bx = rem - by * nx;
    int r0 = by * 16;
    int nr = min(16, R - r0);
    for (int rp = 0; rp < 16; rp += 8) {
        int rr = rp + (tid >> 5), cg = tid & 31;
        int gr = r0 + rr;
        if (gr == 2 * d) {
            for (int c = cg; c < C; c += 32)
                Wl[c * 16 + rr] = up[c] + up[C + c] + up[2 * C + c] + up[3 * C + c];
        } else {
            const float* rowsrc;
            if (gr < d) rowsrc = wq + (size_t)gr * C;
            else if (gr < 2 * d) rowsrc = wk + (size_t)(gr - d) * C;
            else if (gr < R) rowsrc = A.w1 + (size_t)(gr - 2 * d - 1) * 896 + w1off;
            else rowsrc = nullptr;
            if (rowsrc) {
                for (int c = cg; c < C; c += 32) Wl[c * 16 + rr] = rowsrc[c];
            } else {
                for (int c = cg; c < C; c += 32) Wl[c * 16 + rr] = 0.f;
            }
        }
    }
    if (tid < 16) {
        int g2 = r0 + tid;
        float bv2;
        if (g2 < d) bv2 = bq[g2];
        else if (g2 < 2 * d) bv2 = bk[g2 - d];
        else if (g2 == 2 * d) bv2 = ub[0] + ub[1] + ub[2] + ub[3];
        else bv2 = 0.f;
        bl[tid] = bv2;
    }
    __syncthreads();
    int lane = tid & 63, strip = tid >> 6;
    int m0 = bx * 256 + lane * 4;
    const float* xb = x + (size_t)(b * C) * Ns + m0;
    float acc[16][4];
#pragma unroll
    for (int r = 0; r < 16; ++r)
#pragma unroll
        for (int j = 0; j < 4; ++j) acc[r][j] = 0.f;
    float4 buf[4];
#pragma unroll
    for (int j = 0; j < 4; ++j)
        buf[j] = *(const float4*)&xb[(size_t)(strip + 4 * j) * Ns];
    for (int c0 = strip; c0 < C; c0 += 16) {
#pragma unroll
        for (int j = 0; j < 4; ++j) {
            int c = c0 + 4 * j;
            float4 xv = buf[j];
            int cn = c + 16;
            if (cn < C) buf[j] = *(const float4*)&xb[(size_t)cn * Ns];
            const float* wl = &Wl[c * 16];
#pragma unroll
            for (int r4 = 0; r4 < 4; ++r4) {
                float4 w = *(const float4*)&wl[r4 * 4];
                acc[r4 * 4 + 0][0] += w.x * xv.x; acc[r4 * 4 + 0][1] += w.x * xv.y;
                acc[r4 * 4 + 0][2] += w.x * xv.z; acc[r4 * 4 + 0][3] += w.x * xv.w;
                acc[r4 * 4 + 1][0] += w.y * xv.x; acc[r4 * 4 + 1][1] += w.y * xv.y;
                acc[r4 * 4 + 1][2] += w.y * xv.z; acc[r4 * 4 + 1][3] += w.y * xv.w;
                acc[r4 * 4 + 2][0] += w.z * xv.x; acc[r4 * 4 + 2][1] += w.z * xv.y;
                acc[r4 * 4 + 2][2] += w.z * xv.z; acc[r4 * 4 + 2][3] += w.z * xv.w;
                acc[r4 * 4 + 3][0] += w.w * xv.x; acc[r4 * 4 + 3][1] += w.w * xv.y;
                acc[r4 * 4 + 3][2] += w.w * xv.z; acc[r4 * 4 + 3][3] += w.w * xv.w;
            }
        }
    }
    for (int rp = 0; rp < 16; rp += 4) {
        __syncthreads();
#pragma unroll
        for (int r = 0; r < 4; ++r)
#pragma unroll
            for (int j = 0; j < 4; ++j)
                red[((r * 4 + j) * 4 + strip) * 64 + lane] = acc[rp + r][j];
        __syncthreads();
        int g = tid >> 6;
        int rr2 = rp + g;
        if (rr2 < nr) {
            float v[4];
#pragma unroll
            for (int j = 0; j < 4; ++j) {
                int base = (g * 4 + j) * 4 * 64 + lane;
                v[j] = red[base] + red[base + 64] + red[base + 128] + red[base + 192] + bl[rr2];
            }
            *(float4*)&out[(size_t)(b * R + r0 + rr2) * Ns + m0] =
                make_float4(v[0], v[1], v[2], v[3]);
        }
    }
}

// --------------------------- hi/lo split helper ----------------------------
__device__ inline void split_bf16(float f, ushort& hi, ushort& lo) {
    unsigned u = __float_as_uint(f);
    unsigned h = u >> 16;
    float r = f - __uint_as_float(h << 16);
    hi = (ushort)h;
    lo = (ushort)(__float_as_uint(r) >> 16);
}

// --------------------------- bilerp field values ---------------------------
template <int D, int HS>
__device__ void bilerp_vals(const float* __restrict__ proj, int R, int rowbase,
                            float scale, int b, int n, float* vals) {
    constexpr int NS = HS * HS;
    constexpr float f = (float)(HS - 1) / 63.0f;
    int oy = n >> 6, ox = n & 63;
    float cy = oy * f, cx = ox * f;
    int iy0 = min((int)cy, HS - 2);
    int ix0 = min((int)cx, HS - 2);
    float wy = cy - iy0, wx = cx - ix0;
    float w00 = (1.f - wy) * (1.f - wx) * scale, w01 = (1.f - wy) * wx * scale;
    float w10 = wy * (1.f - wx) * scale, w11 = wy * wx * scale;
    const float* pb = proj + ((size_t)b * R + rowbase) * NS + iy0 * HS + ix0;
#pragma unroll
    for (int d = 0; d < D; ++d) {
        const float* p = pb + (size_t)d * NS;
        vals[d] = w00 * p[0] + w01 * p[1] + w10 * p[HS] + w11 * p[HS + 1];
    }
}

// --------------------------- q pack ([n][2D] layout) -----------------------
template <int D>
__device__ void q_store(ushort* __restrict__ dst, const float* vals, int b, int n) {
    ushort outv[2 * D];
#pragma unroll
    for (int d = 0; d < D; ++d) split_bf16(vals[d], outv[d], outv[D + d]);
    ushort* dp = dst + (size_t)(b * 4096 + n) * (2 * D);
#pragma unroll
    for (int i = 0; i < D / 4; ++i)
        ((uint4*)dp)[i] = ((const uint4*)outv)[i];
}

// --------------------------- k pack (fragment order) -----------------------
template <int D>
__device__ void k_store(ushort* __restrict__ dst, const float* vals, int b, int n) {
    constexpr int NC = (D == 16) ? 2 : (D / 32) * 2;
    ushort hi[D], lo[D];
#pragma unroll
    for (int d = 0; d < D; ++d) split_bf16(vals[d], hi[d], lo[d]);
    int tile = n >> 4, cc = n & 15;
    ushort* kb = dst + (size_t)b * (256 * NC * 512) + (size_t)tile * (NC * 512);
    if constexpr (D == 16) {
#pragma unroll
        for (int combo = 0; combo < 2; ++combo)
#pragma unroll
            for (int quad = 0; quad < 4; ++quad) {
                const ushort* src = (combo == 0 ? hi : lo) + (quad & 1) * 8;
                ushort* dp = kb + ((size_t)combo * 512 + (quad * 16 + cc) * 8);
                *(uint4*)dp = *(const uint4*)src;
            }
    } else {
#pragma unroll
        for (int h = 0; h < D / 32; ++h)
#pragma unroll
            for (int part = 0; part < 2; ++part) {
                int combo = h * 2 + part;
#pragma unroll
                for (int quad = 0; quad < 4; ++quad) {
                    const ushort* src = (part == 0 ? hi : lo) + h * 32 + quad * 8;
                    ushort* dp = kb + ((size_t)combo * 512 + (quad * 16 + cc) * 8);
                    *(uint4*)dp = *(const uint4*)src;
                }
            }
    }
}

// --------------------------- native field values (scale2) ------------------
__device__ void nat_vals(const float* __restrict__ proj, int rowbase, float scale,
                         int b, int n, float* vals) {
    const float* pb = proj + ((size_t)b * 65 + rowbase) * 4096 + n;
#pragma unroll
    for (int d = 0; d < 16; ++d) vals[d] = pb[(size_t)d * 4096] * scale;
}

// --------------------------- mid: upsample-s + packs -----------------------
__global__ __launch_bounds__(256) void mid_kernel(float* ws) {
    int idx = blockIdx.x, tid = threadIdx.x;
    if (idx < 128) {
        int gi = idx * 256 + tid;
        int seg = gi >> 14;
        int li = gi & 16383;
        int b = li >> 12, n = li & 4095;
        const float* src;
        float* dst;
        int hs;
        if (seg == 0) { src = ws + OFF_PROJ0 + (b * 161 + 128) * 256;  dst = ws + OFF_SBIG0; hs = 16; }
        else          { src = ws + OFF_PROJ1 + (b * 97 + 64) * 1024;   dst = ws + OFF_SBIG1; hs = 32; }
        int oy = n >> 6, ox = n & 63;
        float f = (float)(hs - 1) / 63.0f;
        float cy = oy * f, cx = ox * f;
        int iy0 = min((int)cy, hs - 2);
        int ix0 = min((int)cx, hs - 2);
        float wy = cy - iy0, wx = cx - ix0;
        float v00 = src[iy0 * hs + ix0], v01 = src[iy0 * hs + ix0 + 1];
        float v10 = src[(iy0 + 1) * hs + ix0], v11 = src[(iy0 + 1) * hs + ix0 + 1];
        float t0 = v00 + wx * (v01 - v00), t1 = v10 + wx * (v11 - v10);
        dst[b * 4096 + n] = t0 + wy * (t1 - t0);
    } else if (idx < 256) {
        int li = idx - 128;
        int field = li >> 6, b = (li >> 4) & 3, nt = li & 15;
        int n = nt * 256 + tid;
        float vals[64];
        if (field == 0) {
            bilerp_vals<64, 16>(ws + OFF_PROJ0, 161, 0, LOG2E, b, n, vals);
            q_store<64>((ushort*)(ws + OFF_QP0), vals, b, n);
        } else {
            bilerp_vals<64, 16>(ws + OFF_PROJ0, 161, 64, 1.0f, b, n, vals);
            k_store<64>((ushort*)(ws + OFF_KF0), vals, b, n);
        }
    } else if (idx < 384) {
        int li = idx - 256;
        int field = li >> 6, b = (li >> 4) & 3, nt = li & 15;
        int n = nt * 256 + tid;
        float vals[32];
        if (field == 0) {
            bilerp_vals<32, 32>(ws + OFF_PROJ1, 97, 0, LOG2E, b, n, vals);
            q_store<32>((ushort*)(ws + OFF_QP1), vals, b, n);
        } else {
            bilerp_vals<32, 32>(ws + OFF_PROJ1, 97, 32, 1.0f, b, n, vals);
            k_store<32>((ushort*)(ws + OFF_KF1), vals, b, n);
        }
    } else {
        int li = idx - 384;
        int field = li >> 6, b = (li >> 4) & 3, nt = li & 15;
        int n = nt * 256 + tid;
        float vals[16];
        if (field == 0) {
            nat_vals(ws + OFF_PROJ2, 0, LOG2E, b, n, vals);
            q_store<16>((ushort*)(ws + OFF_QP2), vals, b, n);
        } else {
            nat_vals(ws + OFF_PROJ2, 16, 1.0f, b, n, vals);
            k_store<16>((ushort*)(ws + OFF_KF2), vals, b, n);
        }
    }
}

// --------------------------- MFMA attention body ---------------------------
// Wave = 16-n tile over 1024-m chunk, fragment-ordered k. Single accumulator
// per tile (keeps VGPR<64 -> max occupancy; R13 showed bigger acc arrays
// halve occupancy). One-tile-ahead register prefetch of k frags + s hides
// the L2 round trip behind the current tile's MFMA+exp. Exact split-bf16
// product, MFMA order identical to R12 (bit-exact).
template <int D>
__device__ void attn_mfma_body(const ushort* __restrict__ qp, const ushort* __restrict__ kf,
                               const float* __restrict__ srow,
                               float* __restrict__ pSn, float* __restrict__ pSw,
                               int nblk, int mc, int b, int tid) {
    constexpr int NC = (D == 16) ? 2 : (D / 32) * 2;
    int wave = tid >> 6, lane = tid & 63;
    int cc = lane & 15, quad = lane >> 4;
    int n0 = (nblk * 4 + wave) * 16;
    const ushort* qn = qp + (size_t)(b * 4096 + n0 + cc) * (2 * D);
    constexpr int NF = (D >= 32) ? (D / 32) : 1;
    short8 Ah[NF], Al[NF];
    if constexpr (D == 16) {
        Ah[0] = *(const short8*)(qn + quad * 8);   // [qh16|ql16] spans k=0..31
    } else {
#pragma unroll
        for (int h = 0; h < NF; ++h) {
            Ah[h] = *(const short8*)(qn + h * 32 + quad * 8);
            Al[h] = *(const short8*)(qn + D + h * 32 + quad * 8);
        }
    }
    const ushort* kfb = kf + (size_t)b * (256 * NC * 512) + lane * 8;
    float Sn[4] = {0.f, 0.f, 0.f, 0.f};
    float Sw[4] = {0.f, 0.f, 0.f, 0.f};
    int tbase = mc * 64;
    // prime the pipeline: tile 0 of the chunk
    short8 Bcur[NC];
    {
        const ushort* kt = kfb + (size_t)tbase * (NC * 512);
#pragma unroll
        for (int cb = 0; cb < NC; ++cb) Bcur[cb] = *(const short8*)(kt + cb * 512);
    }
    float svc = srow[tbase * 16 + cc];
#pragma unroll 2
    for (int mt = 0; mt < 64; ++mt) {
        // prefetch next tile (clamped re-load of last tile on final iter)
        int nx = (mt < 63) ? (mt + 1) : 63;
        const ushort* kn = kfb + (size_t)(tbase + nx) * (NC * 512);
        short8 Bnxt[NC];
#pragma unroll
        for (int cb = 0; cb < NC; ++cb) Bnxt[cb] = *(const short8*)(kn + cb * 512);
        float svn = srow[(tbase + nx) * 16 + cc];
        // compute on current tile (R12 MFMA order)
        f32x4 c = {0.f, 0.f, 0.f, 0.f};
        if constexpr (D == 16) {
            c = __builtin_amdgcn_mfma_f32_16x16x32_bf16(Ah[0], Bcur[1], c, 0, 0, 0);
            c = __builtin_amdgcn_mfma_f32_16x16x32_bf16(Ah[0], Bcur[0], c, 0, 0, 0);
        } else {
#pragma unroll
            for (int h = 0; h < NF; ++h) {
                c = __builtin_amdgcn_mfma_f32_16x16x32_bf16(Ah[h], Bcur[h * 2 + 1], c, 0, 0, 0);
                c = __builtin_amdgcn_mfma_f32_16x16x32_bf16(Al[h], Bcur[h * 2], c, 0, 0, 0);
                c = __builtin_amdgcn_mfma_f32_16x16x32_bf16(Al[h], Bcur[h * 2 + 1], c, 0, 0, 0);
                c = __builtin_amdgcn_mfma_f32_16x16x32_bf16(Ah[h], Bcur[h * 2], c, 0, 0, 0);
            }
        }
#pragma unroll
        for (int r = 0; r < 4; ++r) {
            float e = exp2f(c[r]);
            Sn[r] += e;
            Sw[r] += e * svc;
        }
#pragma unroll
        for (int cb = 0; cb < NC; ++cb) Bcur[cb] = Bnxt[cb];
        svc = svn;
    }
#pragma unroll
    for (int mask = 1; mask < 16; mask <<= 1) {
#pragma unroll
        for (int r = 0; r < 4; ++r) {
            Sn[r] += __shfl_xor(Sn[r], mask, 64);
            Sw[r] += __shfl_xor(Sw[r], mask, 64);
        }
    }
    if (cc == 0) {
        int n = n0 + quad * 4;
        int pidx = (b * 4 + mc) * 4096 + n;
        *(float4*)&pSn[pidx] = make_float4(Sn[0], Sn[1], Sn[2], Sn[3]);
        *(float4*)&pSw[pidx] = make_float4(Sw[0], Sw[1], Sw[2], Sw[3]);
    }
}

// --------------------------- attn: all three scales ------------------------
__global__ __launch_bounds__(256) void attn_kernel(float* ws) {
    int idx = blockIdx.x, tid = threadIdx.x;
    int li = idx & 1023;
    int nblk = li & 63, mc = (li >> 6) & 3, b = li >> 8;
    if (idx < 1024) {
        attn_mfma_body<64>((const ushort*)(ws + OFF_QP0), (const ushort*)(ws + OFF_KF0),
                           ws + OFF_SBIG0 + b * 4096,
                           ws + OFF_PSN0, ws + OFF_PSW0, nblk, mc, b, tid);
    } else if (idx < 2048) {
        attn_mfma_body<32>((const ushort*)(ws + OFF_QP1), (const ushort*)(ws + OFF_KF1),
                           ws + OFF_SBIG1 + b * 4096,
                           ws + OFF_PSN1, ws + OFF_PSW1, nblk, mc, b, tid);
    } else {
        attn_mfma_body<16>((const ushort*)(ws + OFF_QP2), (const ushort*)(ws + OFF_KF2),
                           ws + OFF_PROJ2 + ((size_t)b * 65 + 32) * 4096,
                           ws + OFF_PSN2, ws + OFF_PSW2, nblk, mc, b, tid);
    }
}

// --------------------------- final: combine + fusion -----------------------
__global__ __launch_bounds__(256) void final_kernel(const float* __restrict__ ws,
                                                    const float* __restrict__ ba0,
                                                    const float* __restrict__ ba1,
                                                    const float* __restrict__ ba2,
                                                    const float* __restrict__ b1,
                                                    const float* __restrict__ w2,
                                                    const float* __restrict__ b2,
                                                    float* __restrict__ out) {
    __shared__ float lb1[32], lw2[32];
    int tid = threadIdx.x;
    if (tid < 32) { lb1[tid] = b1[tid]; lw2[tid] = w2[tid]; }
    __syncthreads();
    int b = blockIdx.y;
    int n = blockIdx.x * 256 + tid;
    const float* pSns[3] = {ws + OFF_PSN0, ws + OFF_PSN1, ws + OFF_PSN2};
    const float* pSws[3] = {ws + OFF_PSW0, ws + OFF_PSW1, ws + OFF_PSW2};
    float aval[3];
#pragma unroll
    for (int s = 0; s < 3; ++s) {
        float Sn = 0.f, Sw = 0.f;
#pragma unroll
        for (int ch = 0; ch < 4; ++ch) {
            int pi = (b * 4 + ch) * 4096 + n;
            Sn += pSns[s][pi];
            Sw += pSws[s][pi];
        }
        float bav = (s == 0) ? ba0[0] : (s == 1) ? ba1[0] : ba2[0];
        aval[s] = Sw / Sn + bav;
    }
    float prod = aval[0] * aval[1] * aval[2];
    int oy = n >> 6, ox = n & 63;
    float f0 = 15.0f / 63.0f;
    float cy0 = oy * f0, cx0 = ox * f0;
    int iy0 = min((int)cy0, 14), ix0 = min((int)cx0, 14);
    float wy0 = cy0 - iy0, wx0 = cx0 - ix0;
    float f1 = 31.0f / 63.0f;
    float cy1 = oy * f1, cx1 = ox * f1;
    int iy1 = min((int)cy1, 30), ix1 = min((int)cx1, 30);
    float wy1 = cy1 - iy1, wx1 = cx1 - ix1;
    const float* g0b = ws + OFF_PROJ0 + (b * 161 + 129) * 256;
    const float* g1b = ws + OFF_PROJ1 + (b * 97 + 65) * 1024;
    const float* g2b = ws + OFF_PROJ2 + (b * 65 + 33) * 4096;
    float outv = 0.f;
#pragma unroll 4
    for (int j = 0; j < 32; ++j) {
        const float* p0 = g0b + j * 256;
        float v0 = (1.f - wy0) * ((1.f - wx0) * p0[iy0 * 16 + ix0] + wx0 * p0[iy0 * 16 + ix0 + 1]) +
                   wy0 * ((1.f - wx0) * p0[(iy0 + 1) * 16 + ix0] + wx0 * p0[(iy0 + 1) * 16 + ix0 + 1]);
        const float* p1 = g1b + j * 1024;
        float v1 = (1.f - wy1) * ((1.f - wx1) * p1[iy1 * 32 + ix1] + wx1 * p1[iy1 * 32 + ix1 + 1]) +
                   wy1 * ((1.f - wx1) * p1[(iy1 + 1) * 32 + ix1] + wx1 * p1[(iy1 + 1) * 32 + ix1 + 1]);
        float g = g2b[j * 4096 + n] + v0 + v1;
        float h = fmaxf(prod * g + lb1[j], 0.f);
        outv += lw2[j] * h;
    }
    out[b * 4096 + n] = outv + b2[0];
}

// ---------------------------------------------------------------------------
extern "C" void kernel_launch(void* const* d_in, const int* in_sizes, int n_in,
                              void* d_out, int out_size, void* d_ws, size_t ws_size,
                              hipStream_t stream) {
    const float* x3 = (const float*)d_in[0];
    const float* x2 = (const float*)d_in[1];
    const float* x1 = (const float*)d_in[2];
    const float* W[24];
    for (int i = 0; i < 24; ++i) W[i] = (const float*)d_in[3 + i];
    const float* w1 = (const float*)d_in[27];
    const float* b1 = (const float*)d_in[28];
    const float* w2 = (const float*)d_in[29];
    const float* b2 = (const float*)d_in[30];
    float* ws = (float*)d_ws;
    float* out = (float*)d_out;

    UArgs ua;
    ua.wv0 = W[4];  ua.wa0 = W[6];  ua.bv0 = W[5];
    ua.wv1 = W[12]; ua.wa1 = W[14]; ua.bv1 = W[13];
    ua.wv2 = W[20]; ua.wa2 = W[22]; ua.bv2 = W[21];
    ua.ws = ws;
    u_kernel<<<56, 256, 0, stream>>>(ua);

    ProjArgs ja;
    ja.x0 = x1; ja.x1 = x2; ja.x2 = x3;
    ja.wq0 = W[0];  ja.wk0 = W[2];  ja.bq0 = W[1];  ja.bk0 = W[3];
    ja.wq1 = W[8];  ja.wk1 = W[10]; ja.bq1 = W[9];  ja.bk1 = W[11];
    ja.wq2 = W[16]; ja.wk2 = W[18]; ja.bq2 = W[17]; ja.bk2 = W[19];
    ja.w1 = w1; ja.ws = ws;
    proj_kernel<<<476, 256, 0, stream>>>(ja);

    mid_kernel<<<512, 256, 0, stream>>>(ws);

    attn_kernel<<<3072, 256, 0, stream>>>(ws);

    final_kernel<<<dim3(16, BB), 256, 0, stream>>>(ws, W[7], W[15], W[23],
                                                   b1, w2, b2, out);
}

// Round 15
// 266.996 us; speedup vs baseline: 1.0959x; 1.0351x over previous
//
#include <hip/hip_runtime.h>

// ---------------------------------------------------------------------------
// MultiScaleFeatureFusion — R15 (= R14 with attn: raw v_exp_f32 via
// __builtin_amdgcn_exp2f + strength-reduced running pointers, no prefetch).
//   scale0: x1 [4,512,16,16]  d=64 C=512 hs=16 Ns=256  R=161
//   scale1: x2 [4,256,32,32]  d=32 C=256 hs=32 Ns=1024 R=97
//   scale2: x3 [4,128,64,64]  d=16 C=128 hs=64 Ns=4096 R=65
// u -> proj (16 rows/block) -> mid (upsample s + bilerp + bf16 hi/lo pack,
// k in fragment order) -> attn (split-bf16 MFMA QK^T, exact) -> final.
// No-max softmax (exact: logits bounded, common scale cancels in Sw/Sn).
// ---------------------------------------------------------------------------

#define BB 4
#define LOG2E 1.44269504088896340736f

typedef __attribute__((ext_vector_type(8))) short short8;
typedef __attribute__((ext_vector_type(4))) float f32x4;

static constexpr int OFF_UP0 = 0;                        // [4][512]
static constexpr int OFF_UP1 = OFF_UP0 + 4 * 512;
static constexpr int OFF_UP2 = OFF_UP1 + 4 * 256;
static constexpr int OFF_UB0 = OFF_UP2 + 4 * 128;
static constexpr int OFF_UB1 = OFF_UB0 + 4;
static constexpr int OFF_UB2 = OFF_UB1 + 4;
static constexpr int OFF_PROJ0 = OFF_UB2 + 4;
static constexpr int OFF_PROJ1 = OFF_PROJ0 + BB * 161 * 256;
static constexpr int OFF_PROJ2 = OFF_PROJ1 + BB * 97 * 1024;
static constexpr int OFF_SBIG0 = OFF_PROJ2 + BB * 65 * 4096;   // [b][4096]
static constexpr int OFF_SBIG1 = OFF_SBIG0 + BB * 4096;        // [b][4096]
static constexpr int OFF_QP0 = OFF_SBIG1 + BB * 4096;          // BB*4096*64 fl
static constexpr int OFF_KF0 = OFF_QP0 + BB * 4096 * 64;       // BB*262144 fl
static constexpr int OFF_QP1 = OFF_KF0 + BB * 262144;          // BB*4096*32 fl
static constexpr int OFF_KF1 = OFF_QP1 + BB * 4096 * 32;       // BB*131072 fl
static constexpr int OFF_QP2 = OFF_KF1 + BB * 131072;          // BB*4096*16 fl
static constexpr int OFF_KF2 = OFF_QP2 + BB * 4096 * 16;       // BB*131072 fl
static constexpr int PS = BB * 4 * 4096;
static constexpr int OFF_PSN0 = OFF_KF2 + BB * 131072;
static constexpr int OFF_PSW0 = OFF_PSN0 + PS;
static constexpr int OFF_PSN1 = OFF_PSW0 + PS;
static constexpr int OFF_PSW1 = OFF_PSN1 + PS;
static constexpr int OFF_PSN2 = OFF_PSW1 + PS;
static constexpr int OFF_PSW2 = OFF_PSN2 + PS;

// --------------------------- u partials ------------------------------------
struct UArgs {
    const float *wv0, *wa0, *bv0;
    const float *wv1, *wa1, *bv1;
    const float *wv2, *wa2, *bv2;
    float* ws;
};

__global__ void u_kernel(UArgs A) {
    __shared__ float red[256];
    int idx = blockIdx.x, tid = threadIdx.x;
    int C, cit, chunk;
    const float *wv, *wa, *bv;
    float *up, *ub;
    if (idx < 32) {
        C = 512; cit = idx >> 2; chunk = idx & 3;
        wv = A.wv0; wa = A.wa0; bv = A.bv0;
        up = A.ws + OFF_UP0; ub = A.ws + OFF_UB0;
    } else if (idx < 48) {
        int i2 = idx - 32;
        C = 256; cit = i2 >> 2; chunk = i2 & 3;
        wv = A.wv1; wa = A.wa1; bv = A.bv1;
        up = A.ws + OFF_UP1; ub = A.ws + OFF_UB1;
    } else {
        int i2 = idx - 48;
        C = 128; cit = i2 >> 2; chunk = i2 & 3;
        wv = A.wv2; wa = A.wa2; bv = A.bv2;
        up = A.ws + OFF_UP2; ub = A.ws + OFF_UB2;
    }
    int lci = tid & 63, sub = tid >> 6;
    int ci = cit * 64 + lci;
    int coBeg = chunk * (C >> 2), coEnd = coBeg + (C >> 2);
    float acc = 0.f;
#pragma unroll 4
    for (int co = coBeg + sub; co < coEnd; co += 4)
        acc += wa[co] * wv[(size_t)co * C + ci];
    red[tid] = acc;
    __syncthreads();
    if (sub == 0)
        up[chunk * C + ci] = red[lci] + red[lci + 64] + red[lci + 128] + red[lci + 192];
    if (cit == 0) {
        __syncthreads();
        float bacc = 0.f;
        for (int co = coBeg + tid; co < coEnd; co += 256) bacc += wa[co] * bv[co];
        red[tid] = bacc;
        __syncthreads();
        for (int off = 128; off > 0; off >>= 1) {
            if (tid < off) red[tid] += red[tid + off];
            __syncthreads();
        }
        if (tid == 0) ub[chunk] = red[0];
    }
}

// --------------------------- proj: all scales, 16 rows/block ---------------
struct ProjArgs {
    const float *x0, *x1, *x2;
    const float *wq0, *wk0, *bq0, *bk0;
    const float *wq1, *wk1, *bq1, *bk1;
    const float *wq2, *wk2, *bq2, *bk2;
    const float *w1;
    float* ws;
};

__global__ __launch_bounds__(256) void proj_kernel(ProjArgs A) {
    __shared__ __align__(16) float Wl[512 * 16];  // [c][rr]
    __shared__ float bl[16];
    __shared__ float red[4096];
    int idx = blockIdx.x, tid = threadIdx.x;
    const float *x, *wq, *wk, *bq, *bk, *up, *ub;
    float* out;
    int C, Ns, R, nx, d, w1off, local;
    if (idx < 44) {
        local = idx; x = A.x0; out = A.ws + OFF_PROJ0;
        wq = A.wq0; wk = A.wk0; bq = A.bq0; bk = A.bk0;
        up = A.ws + OFF_UP0; ub = A.ws + OFF_UB0;
        C = 512; Ns = 256; R = 161; nx = 1; d = 64; w1off = 384;
    } else if (idx < 156) {
        local = idx - 44; x = A.x1; out = A.ws + OFF_PROJ1;
        wq = A.wq1; wk = A.wk1; bq = A.bq1; bk = A.bk1;
        up = A.ws + OFF_UP1; ub = A.ws + OFF_UB1;
        C = 256; Ns = 1024; R = 97; nx = 4; d = 32; w1off = 128;
    } else {
        local = idx - 156; x = A.x2; out = A.ws + OFF_PROJ2;
        wq = A.wq2; wk = A.wk2; bq = A.bq2; bk = A.bk2;
        up = A.ws + OFF_UP2; ub = A.ws + OFF_UB2;
        C = 128; Ns = 4096; R = 65; nx = 16; d = 16; w1off = 0;
    }
    int ny = (R + 15) >> 4;
    int pb = nx * ny;
    int b = local / pb;
    int rem = local - b * pb;
    int by = rem / nx;
    int bx = rem - by * nx;
    int r0 = by * 16;
    int nr = min(16, R - r0);
    for (int rp = 0; rp < 16; rp += 8) {
        int rr = rp + (tid >> 5), cg = tid & 31;
        int gr = r0 + rr;
        if (gr == 2 * d) {
            for (int c = cg; c < C; c += 32)
                Wl[c * 16 + rr] = up[c] + up[C + c] + up[2 * C + c] + up[3 * C + c];
        } else {
            const float* rowsrc;
            if (gr < d) rowsrc = wq + (size_t)gr * C;
            else if (gr < 2 * d) rowsrc = wk + (size_t)(gr - d) * C;
            else if (gr < R) rowsrc = A.w1 + (size_t)(gr - 2 * d - 1) * 896 + w1off;
            else rowsrc = nullptr;
            if (rowsrc) {
                for (int c = cg; c < C; c += 32) Wl[c * 16 + rr] = rowsrc[c];
            } else {
                for (int c = cg; c < C; c += 32) Wl[c * 16 + rr] = 0.f;
            }
        }
    }
    if (tid < 16) {
        int g2 = r0 + tid;
        float bv2;
        if (g2 < d) bv2 = bq[g2];
        else if (g2 < 2 * d) bv2 = bk[g2 - d];
        else if (g2 == 2 * d) bv2 = ub[0] + ub[1] + ub[2] + ub[3];
        else bv2 = 0.f;
        bl[tid] = bv2;
    }
    __syncthreads();
    int lane = tid & 63, strip = tid >> 6;
    int m0 = bx * 256 + lane * 4;
    const float* xb = x + (size_t)(b * C) * Ns + m0;
    float acc[16][4];
#pragma unroll
    for (int r = 0; r < 16; ++r)
#pragma unroll
        for (int j = 0; j < 4; ++j) acc[r][j] = 0.f;
    float4 buf[4];
#pragma unroll
    for (int j = 0; j < 4; ++j)
        buf[j] = *(const float4*)&xb[(size_t)(strip + 4 * j) * Ns];
    for (int c0 = strip; c0 < C; c0 += 16) {
#pragma unroll
        for (int j = 0; j < 4; ++j) {
            int c = c0 + 4 * j;
            float4 xv = buf[j];
            int cn = c + 16;
            if (cn < C) buf[j] = *(const float4*)&xb[(size_t)cn * Ns];
            const float* wl = &Wl[c * 16];
#pragma unroll
            for (int r4 = 0; r4 < 4; ++r4) {
                float4 w = *(const float4*)&wl[r4 * 4];
                acc[r4 * 4 + 0][0] += w.x * xv.x; acc[r4 * 4 + 0][1] += w.x * xv.y;
                acc[r4 * 4 + 0][2] += w.x * xv.z; acc[r4 * 4 + 0][3] += w.x * xv.w;
                acc[r4 * 4 + 1][0] += w.y * xv.x; acc[r4 * 4 + 1][1] += w.y * xv.y;
                acc[r4 * 4 + 1][2] += w.y * xv.z; acc[r4 * 4 + 1][3] += w.y * xv.w;
                acc[r4 * 4 + 2][0] += w.z * xv.x; acc[r4 * 4 + 2][1] += w.z * xv.y;
                acc[r4 * 4 + 2][2] += w.z * xv.z; acc[r4 * 4 + 2][3] += w.z * xv.w;
                acc[r4 * 4 + 3][0] += w.w * xv.x; acc[r4 * 4 + 3][1] += w.w * xv.y;
                acc[r4 * 4 + 3][2] += w.w * xv.z; acc[r4 * 4 + 3][3] += w.w * xv.w;
            }
        }
    }
    for (int rp = 0; rp < 16; rp += 4) {
        __syncthreads();
#pragma unroll
        for (int r = 0; r < 4; ++r)
#pragma unroll
            for (int j = 0; j < 4; ++j)
                red[((r * 4 + j) * 4 + strip) * 64 + lane] = acc[rp + r][j];
        __syncthreads();
        int g = tid >> 6;
        int rr2 = rp + g;
        if (rr2 < nr) {
            float v[4];
#pragma unroll
            for (int j = 0; j < 4; ++j) {
                int base = (g * 4 + j) * 4 * 64 + lane;
                v[j] = red[base] + red[base + 64] + red[base + 128] + red[base + 192] + bl[rr2];
            }
            *(float4*)&out[(size_t)(b * R + r0 + rr2) * Ns + m0] =
                make_float4(v[0], v[1], v[2], v[3]);
        }
    }
}

// --------------------------- hi/lo split helper ----------------------------
__device__ inline void split_bf16(float f, ushort& hi, ushort& lo) {
    unsigned u = __float_as_uint(f);
    unsigned h = u >> 16;
    float r = f - __uint_as_float(h << 16);
    hi = (ushort)h;
    lo = (ushort)(__float_as_uint(r) >> 16);
}

// --------------------------- bilerp field values ---------------------------
template <int D, int HS>
__device__ void bilerp_vals(const float* __restrict__ proj, int R, int rowbase,
                            float scale, int b, int n, float* vals) {
    constexpr int NS = HS * HS;
    constexpr float f = (float)(HS - 1) / 63.0f;
    int oy = n >> 6, ox = n & 63;
    float cy = oy * f, cx = ox * f;
    int iy0 = min((int)cy, HS - 2);
    int ix0 = min((int)cx, HS - 2);
    float wy = cy - iy0, wx = cx - ix0;
    float w00 = (1.f - wy) * (1.f - wx) * scale, w01 = (1.f - wy) * wx * scale;
    float w10 = wy * (1.f - wx) * scale, w11 = wy * wx * scale;
    const float* pb = proj + ((size_t)b * R + rowbase) * NS + iy0 * HS + ix0;
#pragma unroll
    for (int d = 0; d < D; ++d) {
        const float* p = pb + (size_t)d * NS;
        vals[d] = w00 * p[0] + w01 * p[1] + w10 * p[HS] + w11 * p[HS + 1];
    }
}

// --------------------------- q pack ([n][2D] layout) -----------------------
template <int D>
__device__ void q_store(ushort* __restrict__ dst, const float* vals, int b, int n) {
    ushort outv[2 * D];
#pragma unroll
    for (int d = 0; d < D; ++d) split_bf16(vals[d], outv[d], outv[D + d]);
    ushort* dp = dst + (size_t)(b * 4096 + n) * (2 * D);
#pragma unroll
    for (int i = 0; i < D / 4; ++i)
        ((uint4*)dp)[i] = ((const uint4*)outv)[i];
}

// --------------------------- k pack (fragment order) -----------------------
template <int D>
__device__ void k_store(ushort* __restrict__ dst, const float* vals, int b, int n) {
    constexpr int NC = (D == 16) ? 2 : (D / 32) * 2;
    ushort hi[D], lo[D];
#pragma unroll
    for (int d = 0; d < D; ++d) split_bf16(vals[d], hi[d], lo[d]);
    int tile = n >> 4, cc = n & 15;
    ushort* kb = dst + (size_t)b * (256 * NC * 512) + (size_t)tile * (NC * 512);
    if constexpr (D == 16) {
#pragma unroll
        for (int combo = 0; combo < 2; ++combo)
#pragma unroll
            for (int quad = 0; quad < 4; ++quad) {
                const ushort* src = (combo == 0 ? hi : lo) + (quad & 1) * 8;
                ushort* dp = kb + ((size_t)combo * 512 + (quad * 16 + cc) * 8);
                *(uint4*)dp = *(const uint4*)src;
            }
    } else {
#pragma unroll
        for (int h = 0; h < D / 32; ++h)
#pragma unroll
            for (int part = 0; part < 2; ++part) {
                int combo = h * 2 + part;
#pragma unroll
                for (int quad = 0; quad < 4; ++quad) {
                    const ushort* src = (part == 0 ? hi : lo) + h * 32 + quad * 8;
                    ushort* dp = kb + ((size_t)combo * 512 + (quad * 16 + cc) * 8);
                    *(uint4*)dp = *(const uint4*)src;
                }
            }
    }
}

// --------------------------- native field values (scale2) ------------------
__device__ void nat_vals(const float* __restrict__ proj, int rowbase, float scale,
                         int b, int n, float* vals) {
    const float* pb = proj + ((size_t)b * 65 + rowbase) * 4096 + n;
#pragma unroll
    for (int d = 0; d < 16; ++d) vals[d] = pb[(size_t)d * 4096] * scale;
}

// --------------------------- mid: upsample-s + packs -----------------------
__global__ __launch_bounds__(256) void mid_kernel(float* ws) {
    int idx = blockIdx.x, tid = threadIdx.x;
    if (idx < 128) {
        int gi = idx * 256 + tid;
        int seg = gi >> 14;
        int li = gi & 16383;
        int b = li >> 12, n = li & 4095;
        const float* src;
        float* dst;
        int hs;
        if (seg == 0) { src = ws + OFF_PROJ0 + (b * 161 + 128) * 256;  dst = ws + OFF_SBIG0; hs = 16; }
        else          { src = ws + OFF_PROJ1 + (b * 97 + 64) * 1024;   dst = ws + OFF_SBIG1; hs = 32; }
        int oy = n >> 6, ox = n & 63;
        float f = (float)(hs - 1) / 63.0f;
        float cy = oy * f, cx = ox * f;
        int iy0 = min((int)cy, hs - 2);
        int ix0 = min((int)cx, hs - 2);
        float wy = cy - iy0, wx = cx - ix0;
        float v00 = src[iy0 * hs + ix0], v01 = src[iy0 * hs + ix0 + 1];
        float v10 = src[(iy0 + 1) * hs + ix0], v11 = src[(iy0 + 1) * hs + ix0 + 1];
        float t0 = v00 + wx * (v01 - v00), t1 = v10 + wx * (v11 - v10);
        dst[b * 4096 + n] = t0 + wy * (t1 - t0);
    } else if (idx < 256) {
        int li = idx - 128;
        int field = li >> 6, b = (li >> 4) & 3, nt = li & 15;
        int n = nt * 256 + tid;
        float vals[64];
        if (field == 0) {
            bilerp_vals<64, 16>(ws + OFF_PROJ0, 161, 0, LOG2E, b, n, vals);
            q_store<64>((ushort*)(ws + OFF_QP0), vals, b, n);
        } else {
            bilerp_vals<64, 16>(ws + OFF_PROJ0, 161, 64, 1.0f, b, n, vals);
            k_store<64>((ushort*)(ws + OFF_KF0), vals, b, n);
        }
    } else if (idx < 384) {
        int li = idx - 256;
        int field = li >> 6, b = (li >> 4) & 3, nt = li & 15;
        int n = nt * 256 + tid;
        float vals[32];
        if (field == 0) {
            bilerp_vals<32, 32>(ws + OFF_PROJ1, 97, 0, LOG2E, b, n, vals);
            q_store<32>((ushort*)(ws + OFF_QP1), vals, b, n);
        } else {
            bilerp_vals<32, 32>(ws + OFF_PROJ1, 97, 32, 1.0f, b, n, vals);
            k_store<32>((ushort*)(ws + OFF_KF1), vals, b, n);
        }
    } else {
        int li = idx - 384;
        int field = li >> 6, b = (li >> 4) & 3, nt = li & 15;
        int n = nt * 256 + tid;
        float vals[16];
        if (field == 0) {
            nat_vals(ws + OFF_PROJ2, 0, LOG2E, b, n, vals);
            q_store<16>((ushort*)(ws + OFF_QP2), vals, b, n);
        } else {
            nat_vals(ws + OFF_PROJ2, 16, 1.0f, b, n, vals);
            k_store<16>((ushort*)(ws + OFF_KF2), vals, b, n);
        }
    }
}

// --------------------------- MFMA attention body ---------------------------
// Wave = 16-n tile over 1024-m chunk, fragment-ordered k (lane-consecutive
// 16B loads). Single accumulator per tile (VGPR<64 -> full occupancy; R13's
// bigger acc arrays halved occupancy and regressed). Raw v_exp_f32 via
// __builtin_amdgcn_exp2f; running pointers (no per-tile index math).
// Exact split-bf16 product, MFMA order identical to R12 (bit-exact).
template <int D>
__device__ void attn_mfma_body(const ushort* __restrict__ qp, const ushort* __restrict__ kf,
                               const float* __restrict__ srow,
                               float* __restrict__ pSn, float* __restrict__ pSw,
                               int nblk, int mc, int b, int tid) {
    constexpr int NC = (D == 16) ? 2 : (D / 32) * 2;
    int wave = tid >> 6, lane = tid & 63;
    int cc = lane & 15, quad = lane >> 4;
    int n0 = (nblk * 4 + wave) * 16;
    const ushort* qn = qp + (size_t)(b * 4096 + n0 + cc) * (2 * D);
    constexpr int NF = (D >= 32) ? (D / 32) : 1;
    short8 Ah[NF], Al[NF];
    if constexpr (D == 16) {
        Ah[0] = *(const short8*)(qn + quad * 8);   // [qh16|ql16] spans k=0..31
    } else {
#pragma unroll
        for (int h = 0; h < NF; ++h) {
            Ah[h] = *(const short8*)(qn + h * 32 + quad * 8);
            Al[h] = *(const short8*)(qn + D + h * 32 + quad * 8);
        }
    }
    float Sn[4] = {0.f, 0.f, 0.f, 0.f};
    float Sw[4] = {0.f, 0.f, 0.f, 0.f};
    int tbase = mc * 64;
    const ushort* kt = kf + (size_t)b * (256 * NC * 512) + (size_t)tbase * (NC * 512) + lane * 8;
    const float* sp = srow + tbase * 16 + cc;
#pragma unroll 2
    for (int mt = 0; mt < 64; ++mt) {
        short8 Bf[NC];
#pragma unroll
        for (int cb = 0; cb < NC; ++cb) Bf[cb] = *(const short8*)(kt + cb * 512);
        float sv = *sp;
        f32x4 c = {0.f, 0.f, 0.f, 0.f};
        if constexpr (D == 16) {
            c = __builtin_amdgcn_mfma_f32_16x16x32_bf16(Ah[0], Bf[1], c, 0, 0, 0);
            c = __builtin_amdgcn_mfma_f32_16x16x32_bf16(Ah[0], Bf[0], c, 0, 0, 0);
        } else {
#pragma unroll
            for (int h = 0; h < NF; ++h) {
                c = __builtin_amdgcn_mfma_f32_16x16x32_bf16(Ah[h], Bf[h * 2 + 1], c, 0, 0, 0);
                c = __builtin_amdgcn_mfma_f32_16x16x32_bf16(Al[h], Bf[h * 2], c, 0, 0, 0);
                c = __builtin_amdgcn_mfma_f32_16x16x32_bf16(Al[h], Bf[h * 2 + 1], c, 0, 0, 0);
                c = __builtin_amdgcn_mfma_f32_16x16x32_bf16(Ah[h], Bf[h * 2], c, 0, 0, 0);
            }
        }
#pragma unroll
        for (int r = 0; r < 4; ++r) {
            float e = __builtin_amdgcn_exp2f(c[r]);
            Sn[r] += e;
            Sw[r] += e * sv;
        }
        kt += NC * 512;
        sp += 16;
    }
#pragma unroll
    for (int mask = 1; mask < 16; mask <<= 1) {
#pragma unroll
        for (int r = 0; r < 4; ++r) {
            Sn[r] += __shfl_xor(Sn[r], mask, 64);
            Sw[r] += __shfl_xor(Sw[r], mask, 64);
        }
    }
    if (cc == 0) {
        int n = n0 + quad * 4;
        int pidx = (b * 4 + mc) * 4096 + n;
        *(float4*)&pSn[pidx] = make_float4(Sn[0], Sn[1], Sn[2], Sn[3]);
        *(float4*)&pSw[pidx] = make_float4(Sw[0], Sw[1], Sw[2], Sw[3]);
    }
}

// --------------------------- attn: all three scales ------------------------
__global__ __launch_bounds__(256) void attn_kernel(float* ws) {
    int idx = blockIdx.x, tid = threadIdx.x;
    int li = idx & 1023;
    int nblk = li & 63, mc = (li >> 6) & 3, b = li >> 8;
    if (idx < 1024) {
        attn_mfma_body<64>((const ushort*)(ws + OFF_QP0), (const ushort*)(ws + OFF_KF0),
                           ws + OFF_SBIG0 + b * 4096,
                           ws + OFF_PSN0, ws + OFF_PSW0, nblk, mc, b, tid);
    } else if (idx < 2048) {
        attn_mfma_body<32>((const ushort*)(ws + OFF_QP1), (const ushort*)(ws + OFF_KF1),
                           ws + OFF_SBIG1 + b * 4096,
                           ws + OFF_PSN1, ws + OFF_PSW1, nblk, mc, b, tid);
    } else {
        attn_mfma_body<16>((const ushort*)(ws + OFF_QP2), (const ushort*)(ws + OFF_KF2),
                           ws + OFF_PROJ2 + ((size_t)b * 65 + 32) * 4096,
                           ws + OFF_PSN2, ws + OFF_PSW2, nblk, mc, b, tid);
    }
}

// --------------------------- final: combine + fusion -----------------------
__global__ __launch_bounds__(256) void final_kernel(const float* __restrict__ ws,
                                                    const float* __restrict__ ba0,
                                                    const float* __restrict__ ba1,
                                                    const float* __restrict__ ba2,
                                                    const float* __restrict__ b1,
                                                    const float* __restrict__ w2,
                                                    const float* __restrict__ b2,
                                                    float* __restrict__ out) {
    __shared__ float lb1[32], lw2[32];
    int tid = threadIdx.x;
    if (tid < 32) { lb1[tid] = b1[tid]; lw2[tid] = w2[tid]; }
    __syncthreads();
    int b = blockIdx.y;
    int n = blockIdx.x * 256 + tid;
    const float* pSns[3] = {ws + OFF_PSN0, ws + OFF_PSN1, ws + OFF_PSN2};
    const float* pSws[3] = {ws + OFF_PSW0, ws + OFF_PSW1, ws + OFF_PSW2};
    float aval[3];
#pragma unroll
    for (int s = 0; s < 3; ++s) {
        float Sn = 0.f, Sw = 0.f;
#pragma unroll
        for (int ch = 0; ch < 4; ++ch) {
            int pi = (b * 4 + ch) * 4096 + n;
            Sn += pSns[s][pi];
            Sw += pSws[s][pi];
        }
        float bav = (s == 0) ? ba0[0] : (s == 1) ? ba1[0] : ba2[0];
        aval[s] = Sw / Sn + bav;
    }
    float prod = aval[0] * aval[1] * aval[2];
    int oy = n >> 6, ox = n & 63;
    float f0 = 15.0f / 63.0f;
    float cy0 = oy * f0, cx0 = ox * f0;
    int iy0 = min((int)cy0, 14), ix0 = min((int)cx0, 14);
    float wy0 = cy0 - iy0, wx0 = cx0 - ix0;
    float f1 = 31.0f / 63.0f;
    float cy1 = oy * f1, cx1 = ox * f1;
    int iy1 = min((int)cy1, 30), ix1 = min((int)cx1, 30);
    float wy1 = cy1 - iy1, wx1 = cx1 - ix1;
    const float* g0b = ws + OFF_PROJ0 + (b * 161 + 129) * 256;
    const float* g1b = ws + OFF_PROJ1 + (b * 97 + 65) * 1024;
    const float* g2b = ws + OFF_PROJ2 + (b * 65 + 33) * 4096;
    float outv = 0.f;
#pragma unroll 4
    for (int j = 0; j < 32; ++j) {
        const float* p0 = g0b + j * 256;
        float v0 = (1.f - wy0) * ((1.f - wx0) * p0[iy0 * 16 + ix0] + wx0 * p0[iy0 * 16 + ix0 + 1]) +
                   wy0 * ((1.f - wx0) * p0[(iy0 + 1) * 16 + ix0] + wx0 * p0[(iy0 + 1) * 16 + ix0 + 1]);
        const float* p1 = g1b + j * 1024;
        float v1 = (1.f - wy1) * ((1.f - wx1) * p1[iy1 * 32 + ix1] + wx1 * p1[iy1 * 32 + ix1 + 1]) +
                   wy1 * ((1.f - wx1) * p1[(iy1 + 1) * 32 + ix1] + wx1 * p1[(iy1 + 1) * 32 + ix1 + 1]);
        float g = g2b[j * 4096 + n] + v0 + v1;
        float h = fmaxf(prod * g + lb1[j], 0.f);
        outv += lw2[j] * h;
    }
    out[b * 4096 + n] = outv + b2[0];
}

// ---------------------------------------------------------------------------
extern "C" void kernel_launch(void* const* d_in, const int* in_sizes, int n_in,
                              void* d_out, int out_size, void* d_ws, size_t ws_size,
                              hipStream_t stream) {
    const float* x3 = (const float*)d_in[0];
    const float* x2 = (const float*)d_in[1];
    const float* x1 = (const float*)d_in[2];
    const float* W[24];
    for (int i = 0; i < 24; ++i) W[i] = (const float*)d_in[3 + i];
    const float* w1 = (const float*)d_in[27];
    const float* b1 = (const float*)d_in[28];
    const float* w2 = (const float*)d_in[29];
    const float* b2 = (const float*)d_in[30];
    float* ws = (float*)d_ws;
    float* out = (float*)d_out;

    UArgs ua;
    ua.wv0 = W[4];  ua.wa0 = W[6];  ua.bv0 = W[5];
    ua.wv1 = W[12]; ua.wa1 = W[14]; ua.bv1 = W[13];
    ua.wv2 = W[20]; ua.wa2 = W[22]; ua.bv2 = W[21];
    ua.ws = ws;
    u_kernel<<<56, 256, 0, stream>>>(ua);

    ProjArgs ja;
    ja.x0 = x1; ja.x1 = x2; ja.x2 = x3;
    ja.wq0 = W[0];  ja.wk0 = W[2];  ja.bq0 = W[1];  ja.bk0 = W[3];
    ja.wq1 = W[8];  ja.wk1 = W[10]; ja.bq1 = W[9];  ja.bk1 = W[11];
    ja.wq2 = W[16]; ja.wk2 = W[18]; ja.bq2 = W[17]; ja.bk2 = W[19];
    ja.w1 = w1; ja.ws = ws;
    proj_kernel<<<476, 256, 0, stream>>>(ja);

    mid_kernel<<<512, 256, 0, stream>>>(ws);

    attn_kernel<<<3072, 256, 0, stream>>>(ws);

    final_kernel<<<dim3(16, BB), 256, 0, stream>>>(ws, W[7], W[15], W[23],
                                                   b1, w2, b2, out);
}

// Round 16
// 257.437 us; speedup vs baseline: 1.1366x; 1.0371x over previous
//
#include <hip/hip_runtime.h>

// ---------------------------------------------------------------------------
// MultiScaleFeatureFusion — R16 (= R15 + LDS-staged k in attn).
//   scale0: x1 [4,512,16,16]  d=64 C=512 hs=16 Ns=256  R=161
//   scale1: x2 [4,256,32,32]  d=32 C=256 hs=32 Ns=1024 R=97
//   scale2: x3 [4,128,64,64]  d=16 C=128 hs=64 Ns=4096 R=65
// u -> proj (16 rows/block) -> mid (upsample s + bilerp + bf16 hi/lo pack,
// k in fragment order) -> attn (split-bf16 MFMA QK^T; k-chunk cooperatively
// staged in LDS and shared by the block's 4 waves -> 4x less L2 traffic;
// raw v_exp_f32) -> final. No-max softmax (exact).
// ---------------------------------------------------------------------------

#define BB 4
#define LOG2E 1.44269504088896340736f

typedef __attribute__((ext_vector_type(8))) short short8;
typedef __attribute__((ext_vector_type(4))) float f32x4;

static constexpr int OFF_UP0 = 0;                        // [4][512]
static constexpr int OFF_UP1 = OFF_UP0 + 4 * 512;
static constexpr int OFF_UP2 = OFF_UP1 + 4 * 256;
static constexpr int OFF_UB0 = OFF_UP2 + 4 * 128;
static constexpr int OFF_UB1 = OFF_UB0 + 4;
static constexpr int OFF_UB2 = OFF_UB1 + 4;
static constexpr int OFF_PROJ0 = OFF_UB2 + 4;
static constexpr int OFF_PROJ1 = OFF_PROJ0 + BB * 161 * 256;
static constexpr int OFF_PROJ2 = OFF_PROJ1 + BB * 97 * 1024;
static constexpr int OFF_SBIG0 = OFF_PROJ2 + BB * 65 * 4096;   // [b][4096]
static constexpr int OFF_SBIG1 = OFF_SBIG0 + BB * 4096;        // [b][4096]
static constexpr int OFF_QP0 = OFF_SBIG1 + BB * 4096;          // BB*4096*64 fl
static constexpr int OFF_KF0 = OFF_QP0 + BB * 4096 * 64;       // BB*262144 fl
static constexpr int OFF_QP1 = OFF_KF0 + BB * 262144;          // BB*4096*32 fl
static constexpr int OFF_KF1 = OFF_QP1 + BB * 4096 * 32;       // BB*131072 fl
static constexpr int OFF_QP2 = OFF_KF1 + BB * 131072;          // BB*4096*16 fl
static constexpr int OFF_KF2 = OFF_QP2 + BB * 4096 * 16;       // BB*131072 fl
static constexpr int PS = BB * 4 * 4096;
static constexpr int OFF_PSN0 = OFF_KF2 + BB * 131072;
static constexpr int OFF_PSW0 = OFF_PSN0 + PS;
static constexpr int OFF_PSN1 = OFF_PSW0 + PS;
static constexpr int OFF_PSW1 = OFF_PSN1 + PS;
static constexpr int OFF_PSN2 = OFF_PSW1 + PS;
static constexpr int OFF_PSW2 = OFF_PSN2 + PS;

// --------------------------- u partials ------------------------------------
struct UArgs {
    const float *wv0, *wa0, *bv0;
    const float *wv1, *wa1, *bv1;
    const float *wv2, *wa2, *bv2;
    float* ws;
};

__global__ void u_kernel(UArgs A) {
    __shared__ float red[256];
    int idx = blockIdx.x, tid = threadIdx.x;
    int C, cit, chunk;
    const float *wv, *wa, *bv;
    float *up, *ub;
    if (idx < 32) {
        C = 512; cit = idx >> 2; chunk = idx & 3;
        wv = A.wv0; wa = A.wa0; bv = A.bv0;
        up = A.ws + OFF_UP0; ub = A.ws + OFF_UB0;
    } else if (idx < 48) {
        int i2 = idx - 32;
        C = 256; cit = i2 >> 2; chunk = i2 & 3;
        wv = A.wv1; wa = A.wa1; bv = A.bv1;
        up = A.ws + OFF_UP1; ub = A.ws + OFF_UB1;
    } else {
        int i2 = idx - 48;
        C = 128; cit = i2 >> 2; chunk = i2 & 3;
        wv = A.wv2; wa = A.wa2; bv = A.bv2;
        up = A.ws + OFF_UP2; ub = A.ws + OFF_UB2;
    }
    int lci = tid & 63, sub = tid >> 6;
    int ci = cit * 64 + lci;
    int coBeg = chunk * (C >> 2), coEnd = coBeg + (C >> 2);
    float acc = 0.f;
#pragma unroll 4
    for (int co = coBeg + sub; co < coEnd; co += 4)
        acc += wa[co] * wv[(size_t)co * C + ci];
    red[tid] = acc;
    __syncthreads();
    if (sub == 0)
        up[chunk * C + ci] = red[lci] + red[lci + 64] + red[lci + 128] + red[lci + 192];
    if (cit == 0) {
        __syncthreads();
        float bacc = 0.f;
        for (int co = coBeg + tid; co < coEnd; co += 256) bacc += wa[co] * bv[co];
        red[tid] = bacc;
        __syncthreads();
        for (int off = 128; off > 0; off >>= 1) {
            if (tid < off) red[tid] += red[tid + off];
            __syncthreads();
        }
        if (tid == 0) ub[chunk] = red[0];
    }
}

// --------------------------- proj: all scales, 16 rows/block ---------------
struct ProjArgs {
    const float *x0, *x1, *x2;
    const float *wq0, *wk0, *bq0, *bk0;
    const float *wq1, *wk1, *bq1, *bk1;
    const float *wq2, *wk2, *bq2, *bk2;
    const float *w1;
    float* ws;
};

__global__ __launch_bounds__(256) void proj_kernel(ProjArgs A) {
    __shared__ __align__(16) float Wl[512 * 16];  // [c][rr]
    __shared__ float bl[16];
    __shared__ float red[4096];
    int idx = blockIdx.x, tid = threadIdx.x;
    const float *x, *wq, *wk, *bq, *bk, *up, *ub;
    float* out;
    int C, Ns, R, nx, d, w1off, local;
    if (idx < 44) {
        local = idx; x = A.x0; out = A.ws + OFF_PROJ0;
        wq = A.wq0; wk = A.wk0; bq = A.bq0; bk = A.bk0;
        up = A.ws + OFF_UP0; ub = A.ws + OFF_UB0;
        C = 512; Ns = 256; R = 161; nx = 1; d = 64; w1off = 384;
    } else if (idx < 156) {
        local = idx - 44; x = A.x1; out = A.ws + OFF_PROJ1;
        wq = A.wq1; wk = A.wk1; bq = A.bq1; bk = A.bk1;
        up = A.ws + OFF_UP1; ub = A.ws + OFF_UB1;
        C = 256; Ns = 1024; R = 97; nx = 4; d = 32; w1off = 128;
    } else {
        local = idx - 156; x = A.x2; out = A.ws + OFF_PROJ2;
        wq = A.wq2; wk = A.wk2; bq = A.bq2; bk = A.bk2;
        up = A.ws + OFF_UP2; ub = A.ws + OFF_UB2;
        C = 128; Ns = 4096; R = 65; nx = 16; d = 16; w1off = 0;
    }
    int ny = (R + 15) >> 4;
    int pb = nx * ny;
    int b = local / pb;
    int rem = local - b * pb;
    int by = rem / nx;
    int bx = rem - by * nx;
    int r0 = by * 16;
    int nr = min(16, R - r0);
    for (int rp = 0; rp < 16; rp += 8) {
        int rr = rp + (tid >> 5), cg = tid & 31;
        int gr = r0 + rr;
        if (gr == 2 * d) {
            for (int c = cg; c < C; c += 32)
                Wl[c * 16 + rr] = up[c] + up[C + c] + up[2 * C + c] + up[3 * C + c];
        } else {
            const float* rowsrc;
            if (gr < d) rowsrc = wq + (size_t)gr * C;
            else if (gr < 2 * d) rowsrc = wk + (size_t)(gr - d) * C;
            else if (gr < R) rowsrc = A.w1 + (size_t)(gr - 2 * d - 1) * 896 + w1off;
            else rowsrc = nullptr;
            if (rowsrc) {
                for (int c = cg; c < C; c += 32) Wl[c * 16 + rr] = rowsrc[c];
            } else {
                for (int c = cg; c < C; c += 32) Wl[c * 16 + rr] = 0.f;
            }
        }
    }
    if (tid < 16) {
        int g2 = r0 + tid;
        float bv2;
        if (g2 < d) bv2 = bq[g2];
        else if (g2 < 2 * d) bv2 = bk[g2 - d];
        else if (g2 == 2 * d) bv2 = ub[0] + ub[1] + ub[2] + ub[3];
        else bv2 = 0.f;
        bl[tid] = bv2;
    }
    __syncthreads();
    int lane = tid & 63, strip = tid >> 6;
    int m0 = bx * 256 + lane * 4;
    const float* xb = x + (size_t)(b * C) * Ns + m0;
    float acc[16][4];
#pragma unroll
    for (int r = 0; r < 16; ++r)
#pragma unroll
        for (int j = 0; j < 4; ++j) acc[r][j] = 0.f;
    float4 buf[4];
#pragma unroll
    for (int j = 0; j < 4; ++j)
        buf[j] = *(const float4*)&xb[(size_t)(strip + 4 * j) * Ns];
    for (int c0 = strip; c0 < C; c0 += 16) {
#pragma unroll
        for (int j = 0; j < 4; ++j) {
            int c = c0 + 4 * j;
            float4 xv = buf[j];
            int cn = c + 16;
            if (cn < C) buf[j] = *(const float4*)&xb[(size_t)cn * Ns];
            const float* wl = &Wl[c * 16];
#pragma unroll
            for (int r4 = 0; r4 < 4; ++r4) {
                float4 w = *(const float4*)&wl[r4 * 4];
                acc[r4 * 4 + 0][0] += w.x * xv.x; acc[r4 * 4 + 0][1] += w.x * xv.y;
                acc[r4 * 4 + 0][2] += w.x * xv.z; acc[r4 * 4 + 0][3] += w.x * xv.w;
                acc[r4 * 4 + 1][0] += w.y * xv.x; acc[r4 * 4 + 1][1] += w.y * xv.y;
                acc[r4 * 4 + 1][2] += w.y * xv.z; acc[r4 * 4 + 1][3] += w.y * xv.w;
                acc[r4 * 4 + 2][0] += w.z * xv.x; acc[r4 * 4 + 2][1] += w.z * xv.y;
                acc[r4 * 4 + 2][2] += w.z * xv.z; acc[r4 * 4 + 2][3] += w.z * xv.w;
                acc[r4 * 4 + 3][0] += w.w * xv.x; acc[r4 * 4 + 3][1] += w.w * xv.y;
                acc[r4 * 4 + 3][2] += w.w * xv.z; acc[r4 * 4 + 3][3] += w.w * xv.w;
            }
        }
    }
    for (int rp = 0; rp < 16; rp += 4) {
        __syncthreads();
#pragma unroll
        for (int r = 0; r < 4; ++r)
#pragma unroll
            for (int j = 0; j < 4; ++j)
                red[((r * 4 + j) * 4 + strip) * 64 + lane] = acc[rp + r][j];
        __syncthreads();
        int g = tid >> 6;
        int rr2 = rp + g;
        if (rr2 < nr) {
            float v[4];
#pragma unroll
            for (int j = 0; j < 4; ++j) {
                int base = (g * 4 + j) * 4 * 64 + lane;
                v[j] = red[base] + red[base + 64] + red[base + 128] + red[base + 192] + bl[rr2];
            }
            *(float4*)&out[(size_t)(b * R + r0 + rr2) * Ns + m0] =
                make_float4(v[0], v[1], v[2], v[3]);
        }
    }
}

// --------------------------- hi/lo split helper ----------------------------
__device__ inline void split_bf16(float f, ushort& hi, ushort& lo) {
    unsigned u = __float_as_uint(f);
    unsigned h = u >> 16;
    float r = f - __uint_as_float(h << 16);
    hi = (ushort)h;
    lo = (ushort)(__float_as_uint(r) >> 16);
}

// --------------------------- bilerp field values ---------------------------
template <int D, int HS>
__device__ void bilerp_vals(const float* __restrict__ proj, int R, int rowbase,
                            float scale, int b, int n, float* vals) {
    constexpr int NS = HS * HS;
    constexpr float f = (float)(HS - 1) / 63.0f;
    int oy = n >> 6, ox = n & 63;
    float cy = oy * f, cx = ox * f;
    int iy0 = min((int)cy, HS - 2);
    int ix0 = min((int)cx, HS - 2);
    float wy = cy - iy0, wx = cx - ix0;
    float w00 = (1.f - wy) * (1.f - wx) * scale, w01 = (1.f - wy) * wx * scale;
    float w10 = wy * (1.f - wx) * scale, w11 = wy * wx * scale;
    const float* pb = proj + ((size_t)b * R + rowbase) * NS + iy0 * HS + ix0;
#pragma unroll
    for (int d = 0; d < D; ++d) {
        const float* p = pb + (size_t)d * NS;
        vals[d] = w00 * p[0] + w01 * p[1] + w10 * p[HS] + w11 * p[HS + 1];
    }
}

// --------------------------- q pack ([n][2D] layout) -----------------------
template <int D>
__device__ void q_store(ushort* __restrict__ dst, const float* vals, int b, int n) {
    ushort outv[2 * D];
#pragma unroll
    for (int d = 0; d < D; ++d) split_bf16(vals[d], outv[d], outv[D + d]);
    ushort* dp = dst + (size_t)(b * 4096 + n) * (2 * D);
#pragma unroll
    for (int i = 0; i < D / 4; ++i)
        ((uint4*)dp)[i] = ((const uint4*)outv)[i];
}

// --------------------------- k pack (fragment order) -----------------------
template <int D>
__device__ void k_store(ushort* __restrict__ dst, const float* vals, int b, int n) {
    constexpr int NC = (D == 16) ? 2 : (D / 32) * 2;
    ushort hi[D], lo[D];
#pragma unroll
    for (int d = 0; d < D; ++d) split_bf16(vals[d], hi[d], lo[d]);
    int tile = n >> 4, cc = n & 15;
    ushort* kb = dst + (size_t)b * (256 * NC * 512) + (size_t)tile * (NC * 512);
    if constexpr (D == 16) {
#pragma unroll
        for (int combo = 0; combo < 2; ++combo)
#pragma unroll
            for (int quad = 0; quad < 4; ++quad) {
                const ushort* src = (combo == 0 ? hi : lo) + (quad & 1) * 8;
                ushort* dp = kb + ((size_t)combo * 512 + (quad * 16 + cc) * 8);
                *(uint4*)dp = *(const uint4*)src;
            }
    } else {
#pragma unroll
        for (int h = 0; h < D / 32; ++h)
#pragma unroll
            for (int part = 0; part < 2; ++part) {
                int combo = h * 2 + part;
#pragma unroll
                for (int quad = 0; quad < 4; ++quad) {
                    const ushort* src = (part == 0 ? hi : lo) + h * 32 + quad * 8;
                    ushort* dp = kb + ((size_t)combo * 512 + (quad * 16 + cc) * 8);
                    *(uint4*)dp = *(const uint4*)src;
                }
            }
    }
}

// --------------------------- native field values (scale2) ------------------
__device__ void nat_vals(const float* __restrict__ proj, int rowbase, float scale,
                         int b, int n, float* vals) {
    const float* pb = proj + ((size_t)b * 65 + rowbase) * 4096 + n;
#pragma unroll
    for (int d = 0; d < 16; ++d) vals[d] = pb[(size_t)d * 4096] * scale;
}

// --------------------------- mid: upsample-s + packs -----------------------
__global__ __launch_bounds__(256) void mid_kernel(float* ws) {
    int idx = blockIdx.x, tid = threadIdx.x;
    if (idx < 128) {
        int gi = idx * 256 + tid;
        int seg = gi >> 14;
        int li = gi & 16383;
        int b = li >> 12, n = li & 4095;
        const float* src;
        float* dst;
        int hs;
        if (seg == 0) { src = ws + OFF_PROJ0 + (b * 161 + 128) * 256;  dst = ws + OFF_SBIG0; hs = 16; }
        else          { src = ws + OFF_PROJ1 + (b * 97 + 64) * 1024;   dst = ws + OFF_SBIG1; hs = 32; }
        int oy = n >> 6, ox = n & 63;
        float f = (float)(hs - 1) / 63.0f;
        float cy = oy * f, cx = ox * f;
        int iy0 = min((int)cy, hs - 2);
        int ix0 = min((int)cx, hs - 2);
        float wy = cy - iy0, wx = cx - ix0;
        float v00 = src[iy0 * hs + ix0], v01 = src[iy0 * hs + ix0 + 1];
        float v10 = src[(iy0 + 1) * hs + ix0], v11 = src[(iy0 + 1) * hs + ix0 + 1];
        float t0 = v00 + wx * (v01 - v00), t1 = v10 + wx * (v11 - v10);
        dst[b * 4096 + n] = t0 + wy * (t1 - t0);
    } else if (idx < 256) {
        int li = idx - 128;
        int field = li >> 6, b = (li >> 4) & 3, nt = li & 15;
        int n = nt * 256 + tid;
        float vals[64];
        if (field == 0) {
            bilerp_vals<64, 16>(ws + OFF_PROJ0, 161, 0, LOG2E, b, n, vals);
            q_store<64>((ushort*)(ws + OFF_QP0), vals, b, n);
        } else {
            bilerp_vals<64, 16>(ws + OFF_PROJ0, 161, 64, 1.0f, b, n, vals);
            k_store<64>((ushort*)(ws + OFF_KF0), vals, b, n);
        }
    } else if (idx < 384) {
        int li = idx - 256;
        int field = li >> 6, b = (li >> 4) & 3, nt = li & 15;
        int n = nt * 256 + tid;
        float vals[32];
        if (field == 0) {
            bilerp_vals<32, 32>(ws + OFF_PROJ1, 97, 0, LOG2E, b, n, vals);
            q_store<32>((ushort*)(ws + OFF_QP1), vals, b, n);
        } else {
            bilerp_vals<32, 32>(ws + OFF_PROJ1, 97, 32, 1.0f, b, n, vals);
            k_store<32>((ushort*)(ws + OFF_KF1), vals, b, n);
        }
    } else {
        int li = idx - 384;
        int field = li >> 6, b = (li >> 4) & 3, nt = li & 15;
        int n = nt * 256 + tid;
        float vals[16];
        if (field == 0) {
            nat_vals(ws + OFF_PROJ2, 0, LOG2E, b, n, vals);
            q_store<16>((ushort*)(ws + OFF_QP2), vals, b, n);
        } else {
            nat_vals(ws + OFF_PROJ2, 16, 1.0f, b, n, vals);
            k_store<16>((ushort*)(ws + OFF_KF2), vals, b, n);
        }
    }
}

// --------------------------- MFMA attention body ---------------------------
// Wave = 16-n tile over 1024-m chunk. k-chunk staged through LDS in ST-tile
// stages (ST*NC = 16 -> 16 KB) shared by the block's 4 waves: global k
// traffic /4 vs R15. s values staged alongside. MFMA order identical to
// R12/R15 (bit-exact); raw v_exp_f32; single accumulator (VGPR<64).
template <int D>
__device__ void attn_mfma_body(const ushort* __restrict__ qp, const ushort* __restrict__ kf,
                               const float* __restrict__ srow,
                               float* __restrict__ pSn, float* __restrict__ pSw,
                               int nblk, int mc, int b, int tid,
                               ushort* kst, float* sst) {
    constexpr int NC = (D == 16) ? 2 : (D / 32) * 2;
    constexpr int ST = 16 / NC;       // tiles per stage (LDS = 16 KB)
    int wave = tid >> 6, lane = tid & 63;
    int cc = lane & 15, quad = lane >> 4;
    int n0 = (nblk * 4 + wave) * 16;
    const ushort* qn = qp + (size_t)(b * 4096 + n0 + cc) * (2 * D);
    constexpr int NF = (D >= 32) ? (D / 32) : 1;
    short8 Ah[NF], Al[NF];
    if constexpr (D == 16) {
        Ah[0] = *(const short8*)(qn + quad * 8);   // [qh16|ql16] spans k=0..31
    } else {
#pragma unroll
        for (int h = 0; h < NF; ++h) {
            Ah[h] = *(const short8*)(qn + h * 32 + quad * 8);
            Al[h] = *(const short8*)(qn + D + h * 32 + quad * 8);
        }
    }
    float Sn[4] = {0.f, 0.f, 0.f, 0.f};
    float Sw[4] = {0.f, 0.f, 0.f, 0.f};
    int tbase = mc * 64;
    const uint4* gk = (const uint4*)(kf + (size_t)b * (256 * NC * 512) +
                                     (size_t)tbase * (NC * 512));
    const float* gs = srow + tbase * 16;
    for (int stage = 0; stage < 64 / ST; ++stage) {
        __syncthreads();
        // cooperative stage: ST*NC*512 us = 16 KB = 1024 uint4
#pragma unroll
        for (int i = 0; i < 4; ++i)
            ((uint4*)kst)[tid + i * 256] = gk[stage * 1024 + tid + i * 256];
        if (tid < ST * 16) sst[tid] = gs[stage * ST * 16 + tid];
        __syncthreads();
        const ushort* kl = kst + lane * 8;
#pragma unroll
        for (int t = 0; t < ST; ++t) {
            short8 Bf[NC];
#pragma unroll
            for (int cb = 0; cb < NC; ++cb)
                Bf[cb] = *(const short8*)(kl + (t * NC + cb) * 512);
            float sv = sst[t * 16 + cc];
            f32x4 c = {0.f, 0.f, 0.f, 0.f};
            if constexpr (D == 16) {
                c = __builtin_amdgcn_mfma_f32_16x16x32_bf16(Ah[0], Bf[1], c, 0, 0, 0);
                c = __builtin_amdgcn_mfma_f32_16x16x32_bf16(Ah[0], Bf[0], c, 0, 0, 0);
            } else {
#pragma unroll
                for (int h = 0; h < NF; ++h) {
                    c = __builtin_amdgcn_mfma_f32_16x16x32_bf16(Ah[h], Bf[h * 2 + 1], c, 0, 0, 0);
                    c = __builtin_amdgcn_mfma_f32_16x16x32_bf16(Al[h], Bf[h * 2], c, 0, 0, 0);
                    c = __builtin_amdgcn_mfma_f32_16x16x32_bf16(Al[h], Bf[h * 2 + 1], c, 0, 0, 0);
                    c = __builtin_amdgcn_mfma_f32_16x16x32_bf16(Ah[h], Bf[h * 2], c, 0, 0, 0);
                }
            }
#pragma unroll
            for (int r = 0; r < 4; ++r) {
                float e = __builtin_amdgcn_exp2f(c[r]);
                Sn[r] += e;
                Sw[r] += e * sv;
            }
        }
    }
#pragma unroll
    for (int mask = 1; mask < 16; mask <<= 1) {
#pragma unroll
        for (int r = 0; r < 4; ++r) {
            Sn[r] += __shfl_xor(Sn[r], mask, 64);
            Sw[r] += __shfl_xor(Sw[r], mask, 64);
        }
    }
    if (cc == 0) {
        int n = n0 + quad * 4;
        int pidx = (b * 4 + mc) * 4096 + n;
        *(float4*)&pSn[pidx] = make_float4(Sn[0], Sn[1], Sn[2], Sn[3]);
        *(float4*)&pSw[pidx] = make_float4(Sw[0], Sw[1], Sw[2], Sw[3]);
    }
}

// --------------------------- attn: all three scales ------------------------
__global__ __launch_bounds__(256) void attn_kernel(float* ws) {
    __shared__ __align__(16) ushort kst[16 * 512];   // 16 KB stage buffer
    __shared__ float sst[128];
    int idx = blockIdx.x, tid = threadIdx.x;
    int li = idx & 1023;
    int nblk = li & 63, mc = (li >> 6) & 3, b = li >> 8;
    if (idx < 1024) {
        attn_mfma_body<64>((const ushort*)(ws + OFF_QP0), (const ushort*)(ws + OFF_KF0),
                           ws + OFF_SBIG0 + b * 4096,
                           ws + OFF_PSN0, ws + OFF_PSW0, nblk, mc, b, tid, kst, sst);
    } else if (idx < 2048) {
        attn_mfma_body<32>((const ushort*)(ws + OFF_QP1), (const ushort*)(ws + OFF_KF1),
                           ws + OFF_SBIG1 + b * 4096,
                           ws + OFF_PSN1, ws + OFF_PSW1, nblk, mc, b, tid, kst, sst);
    } else {
        attn_mfma_body<16>((const ushort*)(ws + OFF_QP2), (const ushort*)(ws + OFF_KF2),
                           ws + OFF_PROJ2 + ((size_t)b * 65 + 32) * 4096,
                           ws + OFF_PSN2, ws + OFF_PSW2, nblk, mc, b, tid, kst, sst);
    }
}

// --------------------------- final: combine + fusion -----------------------
__global__ __launch_bounds__(256) void final_kernel(const float* __restrict__ ws,
                                                    const float* __restrict__ ba0,
                                                    const float* __restrict__ ba1,
                                                    const float* __restrict__ ba2,
                                                    const float* __restrict__ b1,
                                                    const float* __restrict__ w2,
                                                    const float* __restrict__ b2,
                                                    float* __restrict__ out) {
    __shared__ float lb1[32], lw2[32];
    int tid = threadIdx.x;
    if (tid < 32) { lb1[tid] = b1[tid]; lw2[tid] = w2[tid]; }
    __syncthreads();
    int b = blockIdx.y;
    int n = blockIdx.x * 256 + tid;
    const float* pSns[3] = {ws + OFF_PSN0, ws + OFF_PSN1, ws + OFF_PSN2};
    const float* pSws[3] = {ws + OFF_PSW0, ws + OFF_PSW1, ws + OFF_PSW2};
    float aval[3];
#pragma unroll
    for (int s = 0; s < 3; ++s) {
        float Sn = 0.f, Sw = 0.f;
#pragma unroll
        for (int ch = 0; ch < 4; ++ch) {
            int pi = (b * 4 + ch) * 4096 + n;
            Sn += pSns[s][pi];
            Sw += pSws[s][pi];
        }
        float bav = (s == 0) ? ba0[0] : (s == 1) ? ba1[0] : ba2[0];
        aval[s] = Sw / Sn + bav;
    }
    float prod = aval[0] * aval[1] * aval[2];
    int oy = n >> 6, ox = n & 63;
    float f0 = 15.0f / 63.0f;
    float cy0 = oy * f0, cx0 = ox * f0;
    int iy0 = min((int)cy0, 14), ix0 = min((int)cx0, 14);
    float wy0 = cy0 - iy0, wx0 = cx0 - ix0;
    float f1 = 31.0f / 63.0f;
    float cy1 = oy * f1, cx1 = ox * f1;
    int iy1 = min((int)cy1, 30), ix1 = min((int)cx1, 30);
    float wy1 = cy1 - iy1, wx1 = cx1 - ix1;
    const float* g0b = ws + OFF_PROJ0 + (b * 161 + 129) * 256;
    const float* g1b = ws + OFF_PROJ1 + (b * 97 + 65) * 1024;
    const float* g2b = ws + OFF_PROJ2 + (b * 65 + 33) * 4096;
    float outv = 0.f;
#pragma unroll 4
    for (int j = 0; j < 32; ++j) {
        const float* p0 = g0b + j * 256;
        float v0 = (1.f - wy0) * ((1.f - wx0) * p0[iy0 * 16 + ix0] + wx0 * p0[iy0 * 16 + ix0 + 1]) +
                   wy0 * ((1.f - wx0) * p0[(iy0 + 1) * 16 + ix0] + wx0 * p0[(iy0 + 1) * 16 + ix0 + 1]);
        const float* p1 = g1b + j * 1024;
        float v1 = (1.f - wy1) * ((1.f - wx1) * p1[iy1 * 32 + ix1] + wx1 * p1[iy1 * 32 + ix1 + 1]) +
                   wy1 * ((1.f - wx1) * p1[(iy1 + 1) * 32 + ix1] + wx1 * p1[(iy1 + 1) * 32 + ix1 + 1]);
        float g = g2b[j * 4096 + n] + v0 + v1;
        float h = fmaxf(prod * g + lb1[j], 0.f);
        outv += lw2[j] * h;
    }
    out[b * 4096 + n] = outv + b2[0];
}

// ---------------------------------------------------------------------------
extern "C" void kernel_launch(void* const* d_in, const int* in_sizes, int n_in,
                              void* d_out, int out_size, void* d_ws, size_t ws_size,
                              hipStream_t stream) {
    const float* x3 = (const float*)d_in[0];
    const float* x2 = (const float*)d_in[1];
    const float* x1 = (const float*)d_in[2];
    const float* W[24];
    for (int i = 0; i < 24; ++i) W[i] = (const float*)d_in[3 + i];
    const float* w1 = (const float*)d_in[27];
    const float* b1 = (const float*)d_in[28];
    const float* w2 = (const float*)d_in[29];
    const float* b2 = (const float*)d_in[30];
    float* ws = (float*)d_ws;
    float* out = (float*)d_out;

    UArgs ua;
    ua.wv0 = W[4];  ua.wa0 = W[6];  ua.bv0 = W[5];
    ua.wv1 = W[12]; ua.wa1 = W[14]; ua.bv1 = W[13];
    ua.wv2 = W[20]; ua.wa2 = W[22]; ua.bv2 = W[21];
    ua.ws = ws;
    u_kernel<<<56, 256, 0, stream>>>(ua);

    ProjArgs ja;
    ja.x0 = x1; ja.x1 = x2; ja.x2 = x3;
    ja.wq0 = W[0];  ja.wk0 = W[2];  ja.bq0 = W[1];  ja.bk0 = W[3];
    ja.wq1 = W[8];  ja.wk1 = W[10]; ja.bq1 = W[9];  ja.bk1 = W[11];
    ja.wq2 = W[16]; ja.wk2 = W[18]; ja.bq2 = W[17]; ja.bk2 = W[19];
    ja.w1 = w1; ja.ws = ws;
    proj_kernel<<<476, 256, 0, stream>>>(ja);

    mid_kernel<<<512, 256, 0, stream>>>(ws);

    attn_kernel<<<3072, 256, 0, stream>>>(ws);

    final_kernel<<<dim3(16, BB), 256, 0, stream>>>(ws, W[7], W[15], W[23],
                                                   b1, w2, b2, out);
}